// Round 1
// baseline (6206.203 us; speedup 1.0000x reference)
//
#include <hip/hip_runtime.h>

// Problem constants (from reference)
#define B_ROWS 4096
#define D      512
#define N_EX   20000
#define N_LAB  100
#define LABP   112      // labels padded to 112 (16 threads x 7) ; pads are zero
#define SPLITS 8
#define NTILES 313      // ceil(20000/64)

__device__ __forceinline__ float wave_reduce_sum(float v) {
    #pragma unroll
    for (int off = 32; off > 0; off >>= 1) v += __shfl_down(v, off, 64);
    return v;
}

// C[m][n] = sum_k X[m][k]*W[n][k]   (X: M x 512, W: 512 x 512) -- i.e. X @ W^T
// BM=BN=64, BK=32, 256 threads, 4x4 register tile, transposed LDS chunks.
__global__ __launch_bounds__(256) void gemm_bt_k(const float* __restrict__ X,
                                                 const float* __restrict__ W,
                                                 float* __restrict__ C, int M) {
    __shared__ float XT[32][68];   // [k][m], stride 68 floats (16B-aligned rows, bank-spread)
    __shared__ float WT[32][68];
    const int tid = threadIdx.x;
    const int tx = tid & 15, ty = tid >> 4;
    const int m0 = blockIdx.x * 64;
    const int n0 = blockIdx.y * 64;
    float acc[4][4] = {};
    for (int kc = 0; kc < 16; ++kc) {
        __syncthreads();
        const int k0 = kc * 32;
        #pragma unroll
        for (int s = 0; s < 2; ++s) {
            int idx = tid + s * 256;
            int r = idx >> 3, c4 = idx & 7;
            float4 xv = {0.f, 0.f, 0.f, 0.f};
            if (m0 + r < M) xv = *(const float4*)&X[(size_t)(m0 + r) * D + k0 + c4 * 4];
            float4 wv = *(const float4*)&W[(size_t)(n0 + r) * D + k0 + c4 * 4];
            XT[c4*4+0][r] = xv.x; XT[c4*4+1][r] = xv.y; XT[c4*4+2][r] = xv.z; XT[c4*4+3][r] = xv.w;
            WT[c4*4+0][r] = wv.x; WT[c4*4+1][r] = wv.y; WT[c4*4+2][r] = wv.z; WT[c4*4+3][r] = wv.w;
        }
        __syncthreads();
        #pragma unroll
        for (int kk = 0; kk < 32; ++kk) {
            float4 av = *(const float4*)&XT[kk][ty * 4];
            float4 bv = *(const float4*)&WT[kk][tx * 4];
            float a_[4] = {av.x, av.y, av.z, av.w};
            float b_[4] = {bv.x, bv.y, bv.z, bv.w};
            #pragma unroll
            for (int i = 0; i < 4; ++i)
                #pragma unroll
                for (int j = 0; j < 4; ++j)
                    acc[i][j] += a_[i] * b_[j];
        }
    }
    #pragma unroll
    for (int i = 0; i < 4; ++i) {
        int row = m0 + ty * 4 + i;
        if (row < M) {
            float4 o = {acc[i][0], acc[i][1], acc[i][2], acc[i][3]};
            *(float4*)&C[(size_t)row * D + n0 + tx * 4] = o;
        }
    }
}

// In-place L2 row normalization, one block (128 thr) per row of 512 floats.
__global__ __launch_bounds__(128) void l2norm_k(float* __restrict__ X) {
    const int row = blockIdx.x, tid = threadIdx.x;
    float4 v = *(float4*)&X[(size_t)row * D + tid * 4];
    float ss = v.x * v.x + v.y * v.y + v.z * v.z + v.w * v.w;
    ss = wave_reduce_sum(ss);
    __shared__ float red[2];
    if ((tid & 63) == 0) red[tid >> 6] = ss;
    __syncthreads();
    float inv = 1.0f / fmaxf(sqrtf(red[0] + red[1]), 1e-12f);
    v.x *= inv; v.y *= inv; v.z *= inv; v.w *= inv;
    *(float4*)&X[(size_t)row * D + tid * 4] = v;
}

// ecr[row][lab] = (l1norm(ex_classes[row]) @ class_reps)[lab]; padded to LABP with zeros.
__global__ __launch_bounds__(128) void ecr_k(const float* __restrict__ exc,
                                             const float* __restrict__ creps,
                                             float* __restrict__ ecr) {
    const int row = blockIdx.x, tid = threadIdx.x;
    __shared__ float aL[N_LAB];
    __shared__ float red[2];
    float v = 0.f;
    if (tid < N_LAB) { v = exc[(size_t)row * N_LAB + tid]; aL[tid] = v; }
    float s = wave_reduce_sum(fabsf(v));
    if ((tid & 63) == 0) red[tid >> 6] = s;
    __syncthreads();
    float inv = 1.0f / fmaxf(red[0] + red[1], 1e-12f);
    if (tid < LABP) {
        float acc = 0.f;
        if (tid < N_LAB) {
            for (int c = 0; c < N_LAB; ++c) acc += aL[c] * creps[c * N_LAB + tid];
            acc *= inv;
        }
        ecr[(size_t)row * LABP + tid] = acc;   // pads (tid>=100) get 0
    }
}

// Fused: s = fn @ en^T (64x64 tiles), cube, accumulate num = s3 @ ecr and den = sum|s3|.
// Grid: (4096/64) x SPLITS. Each block accumulates over its split's exemplar tiles.
__global__ __launch_bounds__(256) void fused_main_k(const float* __restrict__ fn,
                                                    const float* __restrict__ en,
                                                    const float* __restrict__ ecr,
                                                    float* __restrict__ nump,
                                                    float* __restrict__ denp) {
    __shared__ float fnT[32][68];      // [k][m] chunk
    __shared__ float enT[32][68];      // [k][e] chunk
    __shared__ float s3L[64][68];      // cubed scores [m][e]
    __shared__ float ecrT[LABP][68];   // [lab][e]
    __shared__ float denL[64][16];

    const int tid = threadIdx.x;
    const int tx = tid & 15, ty = tid >> 4;   // gemm mapping; reused as (tt, g) in num phase
    const int m0 = blockIdx.x * 64;
    const int split = blockIdx.y;

    float num_acc[4][7] = {};
    float den_r[4] = {};

    for (int t = split; t < NTILES; t += SPLITS) {
        const int e0 = t * 64;
        float sacc[4][4] = {};
        for (int kc = 0; kc < 16; ++kc) {
            __syncthreads();
            const int k0 = kc * 32;
            #pragma unroll
            for (int s = 0; s < 2; ++s) {
                int idx = tid + s * 256;
                int r = idx >> 3, c4 = idx & 7;
                float4 fv = *(const float4*)&fn[(size_t)(m0 + r) * D + k0 + c4 * 4];
                float4 ev = {0.f, 0.f, 0.f, 0.f};
                if (e0 + r < N_EX) ev = *(const float4*)&en[(size_t)(e0 + r) * D + k0 + c4 * 4];
                fnT[c4*4+0][r] = fv.x; fnT[c4*4+1][r] = fv.y; fnT[c4*4+2][r] = fv.z; fnT[c4*4+3][r] = fv.w;
                enT[c4*4+0][r] = ev.x; enT[c4*4+1][r] = ev.y; enT[c4*4+2][r] = ev.z; enT[c4*4+3][r] = ev.w;
            }
            __syncthreads();
            #pragma unroll
            for (int kk = 0; kk < 32; ++kk) {
                float4 av = *(const float4*)&fnT[kk][ty * 4];
                float4 bv = *(const float4*)&enT[kk][tx * 4];
                float a_[4] = {av.x, av.y, av.z, av.w};
                float b_[4] = {bv.x, bv.y, bv.z, bv.w};
                #pragma unroll
                for (int i = 0; i < 4; ++i)
                    #pragma unroll
                    for (int j = 0; j < 4; ++j)
                        sacc[i][j] += a_[i] * b_[j];
            }
        }
        // write cubed tile (sign(s)|s|^3 == s^3)
        #pragma unroll
        for (int i = 0; i < 4; ++i) {
            float4 o;
            o.x = sacc[i][0] * sacc[i][0] * sacc[i][0];
            o.y = sacc[i][1] * sacc[i][1] * sacc[i][1];
            o.z = sacc[i][2] * sacc[i][2] * sacc[i][2];
            o.w = sacc[i][3] * sacc[i][3] * sacc[i][3];
            *(float4*)&s3L[ty * 4 + i][tx * 4] = o;
        }
        // stage ecr^T tile: ecrT[lab][e] = ecr[e0+e][lab]
        #pragma unroll
        for (int s = 0; s < 7; ++s) {
            int idx = tid + s * 256;          // 0..1791 = 64 rows * 28 float4
            int e = idx / 28, l4 = idx % 28;
            int ge = e0 + e;
            float4 v = {0.f, 0.f, 0.f, 0.f};
            if (ge < N_EX) v = *(const float4*)&ecr[(size_t)ge * LABP + l4 * 4];
            ecrT[l4*4+0][e] = v.x; ecrT[l4*4+1][e] = v.y; ecrT[l4*4+2][e] = v.z; ecrT[l4*4+3][e] = v.w;
        }
        __syncthreads();
        // num/den phase: thread (g=ty, tt=tx) owns rows 4g..4g+3, labs {16j+tt}
        #pragma unroll
        for (int e4 = 0; e4 < 16; ++e4) {
            float4 s3v[4];
            #pragma unroll
            for (int i = 0; i < 4; ++i) s3v[i] = *(const float4*)&s3L[4 * ty + i][e4 * 4];
            if (e4 == tx) {
                #pragma unroll
                for (int i = 0; i < 4; ++i)
                    den_r[i] += fabsf(s3v[i].x) + fabsf(s3v[i].y) + fabsf(s3v[i].z) + fabsf(s3v[i].w);
            }
            #pragma unroll
            for (int j = 0; j < 7; ++j) {
                float4 w4 = *(const float4*)&ecrT[16 * j + tx][e4 * 4];
                #pragma unroll
                for (int i = 0; i < 4; ++i)
                    num_acc[i][j] += s3v[i].x * w4.x + s3v[i].y * w4.y + s3v[i].z * w4.z + s3v[i].w * w4.w;
            }
        }
    }
    // reduce den across the 16 threads of each row group, store partials
    #pragma unroll
    for (int i = 0; i < 4; ++i) denL[4 * ty + i][tx] = den_r[i];
    __syncthreads();
    if (tid < 64) {
        float d = 0.f;
        #pragma unroll
        for (int t = 0; t < 16; ++t) d += denL[tid][t];
        denp[split * B_ROWS + m0 + tid] = d;
    }
    #pragma unroll
    for (int i = 0; i < 4; ++i)
        #pragma unroll
        for (int j = 0; j < 7; ++j)
            nump[((size_t)split * B_ROWS + m0 + 4 * ty + i) * LABP + 16 * j + tx] = num_acc[i][j];
}

// echo[row][lab] = sum_s num[s][row][lab] / max(sum_s den[s][row], eps)
__global__ __launch_bounds__(128) void finalize_k(const float* __restrict__ nump,
                                                  const float* __restrict__ denp,
                                                  float* __restrict__ out) {
    const int row = blockIdx.x, tid = threadIdx.x;
    float den = 0.f;
    #pragma unroll
    for (int s = 0; s < SPLITS; ++s) den += denp[s * B_ROWS + row];
    if (tid < N_LAB) {
        float acc = 0.f;
        #pragma unroll
        for (int s = 0; s < SPLITS; ++s) acc += nump[((size_t)s * B_ROWS + row) * LABP + tid];
        out[(size_t)row * N_LAB + tid] = acc / fmaxf(den, 1e-12f);
    }
}

extern "C" void kernel_launch(void* const* d_in, const int* in_sizes, int n_in,
                              void* d_out, int out_size, void* d_ws, size_t ws_size,
                              hipStream_t stream) {
    (void)in_sizes; (void)n_in; (void)out_size; (void)ws_size;
    const float* features    = (const float*)d_in[0];
    const float* g_weight    = (const float*)d_in[1];
    const float* ex_features = (const float*)d_in[2];
    const float* ex_classes  = (const float*)d_in[3];
    const float* class_reps  = (const float*)d_in[4];
    float* out = (float*)d_out;

    // Workspace layout (fp32): ~73 MB total
    float* fn   = (float*)d_ws;                         // 4096*512
    float* en   = fn + (size_t)B_ROWS * D;              // 20000*512
    float* ecr  = en + (size_t)N_EX * D;                // 20000*112
    float* nump = ecr + (size_t)N_EX * LABP;            // 8*4096*112
    float* denp = nump + (size_t)SPLITS * B_ROWS * LABP;// 8*4096

    gemm_bt_k<<<dim3(B_ROWS / 64, 8), 256, 0, stream>>>(features, g_weight, fn, B_ROWS);
    gemm_bt_k<<<dim3((N_EX + 63) / 64, 8), 256, 0, stream>>>(ex_features, g_weight, en, N_EX);
    l2norm_k<<<B_ROWS, 128, 0, stream>>>(fn);
    l2norm_k<<<N_EX, 128, 0, stream>>>(en);
    ecr_k<<<N_EX, 128, 0, stream>>>(ex_classes, class_reps, ecr);
    fused_main_k<<<dim3(B_ROWS / 64, SPLITS), 256, 0, stream>>>(fn, en, ecr, nump, denp);
    finalize_k<<<B_ROWS, 128, 0, stream>>>(nump, denp, out);
}

// Round 2
// 810.787 us; speedup vs baseline: 7.6545x; 7.6545x over previous
//
#include <hip/hip_runtime.h>

#define B_ROWS 4096
#define D      512
#define N_EX   20000
#define EXP    20032     // N_EX padded to multiple of 64
#define N_LAB  100
#define LABP   112       // labels padded to 7x16
#define SPLITS 8
#define NT     313       // ceil(20000/64)

typedef __attribute__((ext_vector_type(8))) short short8v;   // 8 bf16 = 4 VGPR (MFMA A/B frag)
typedef __attribute__((ext_vector_type(4))) short short4v;
typedef __attribute__((ext_vector_type(4))) float f32x4;     // MFMA C/D frag
typedef unsigned short u16;

__device__ __forceinline__ u16 f2bf(float x) {
    unsigned u = __builtin_bit_cast(unsigned, x);
    u = u + 0x7FFFu + ((u >> 16) & 1u);          // RNE
    return (u16)(u >> 16);
}
__device__ __forceinline__ float bf2f(u16 h) {
    unsigned u = ((unsigned)h) << 16;
    return __builtin_bit_cast(float, u);
}

__device__ __forceinline__ float wave_reduce_sum(float v) {
    #pragma unroll
    for (int off = 32; off > 0; off >>= 1) v += __shfl_down(v, off, 64);
    return v;
}

#define MFMA(a, b, c) __builtin_amdgcn_mfma_f32_16x16x32_bf16((a), (b), (c), 0, 0, 0)

// C = X @ W^T via 3-pass split-bf16 MFMA. X: M x 512 fp32, W: 512 x 512 fp32.
// Output written as bf16 hi/lo pair (for the downstream normalize+GEMM).
__global__ __launch_bounds__(256, 2)
void proj_k(const float* __restrict__ X, const float* __restrict__ W,
            u16* __restrict__ Chi, u16* __restrict__ Clo, int M) {
    __shared__ u16 AH[64][72], AL[64][72], BH[64][72], BL[64][72];
    const int tid = threadIdx.x;
    const int lane = tid & 63, wave = tid >> 6;
    const int wm = wave >> 1, wn = wave & 1;
    const int l15 = lane & 15, l4 = lane >> 4;
    const int m0 = blockIdx.x * 64, n0 = blockIdx.y * 64;
    f32x4 acc[2][2] = {};
    for (int kc = 0; kc < 8; ++kc) {
        __syncthreads();
        #pragma unroll
        for (int s = 0; s < 2; ++s) {
            int ix = tid + s * 256;
            int r = ix >> 3, c = ix & 7;
            float va[8] = {0.f,0.f,0.f,0.f,0.f,0.f,0.f,0.f};
            if (m0 + r < M) {
                const float* p = &X[(size_t)(m0 + r) * D + kc * 64 + c * 8];
                float4 t0 = *(const float4*)p, t1 = *(const float4*)(p + 4);
                va[0]=t0.x; va[1]=t0.y; va[2]=t0.z; va[3]=t0.w;
                va[4]=t1.x; va[5]=t1.y; va[6]=t1.z; va[7]=t1.w;
            }
            short8v h, l;
            #pragma unroll
            for (int j = 0; j < 8; ++j) {
                u16 hh = f2bf(va[j]); h[j] = (short)hh; l[j] = (short)f2bf(va[j] - bf2f(hh));
            }
            *(short8v*)&AH[r][c*8] = h; *(short8v*)&AL[r][c*8] = l;
            const float* q = &W[(size_t)(n0 + r) * D + kc * 64 + c * 8];
            float4 s0 = *(const float4*)q, s1 = *(const float4*)(q + 4);
            float vb[8] = {s0.x,s0.y,s0.z,s0.w,s1.x,s1.y,s1.z,s1.w};
            #pragma unroll
            for (int j = 0; j < 8; ++j) {
                u16 hh = f2bf(vb[j]); h[j] = (short)hh; l[j] = (short)f2bf(vb[j] - bf2f(hh));
            }
            *(short8v*)&BH[r][c*8] = h; *(short8v*)&BL[r][c*8] = l;
        }
        __syncthreads();
        #pragma unroll
        for (int ks = 0; ks < 2; ++ks) {
            const int ko = ks * 32 + l4 * 8;
            short8v ah0 = *(const short8v*)&AH[wm*32      + l15][ko];
            short8v ah1 = *(const short8v*)&AH[wm*32 + 16 + l15][ko];
            short8v al0 = *(const short8v*)&AL[wm*32      + l15][ko];
            short8v al1 = *(const short8v*)&AL[wm*32 + 16 + l15][ko];
            short8v bh0 = *(const short8v*)&BH[wn*32      + l15][ko];
            short8v bh1 = *(const short8v*)&BH[wn*32 + 16 + l15][ko];
            short8v bl0 = *(const short8v*)&BL[wn*32      + l15][ko];
            short8v bl1 = *(const short8v*)&BL[wn*32 + 16 + l15][ko];
            acc[0][0] = MFMA(ah0, bh0, acc[0][0]); acc[0][0] = MFMA(ah0, bl0, acc[0][0]); acc[0][0] = MFMA(al0, bh0, acc[0][0]);
            acc[0][1] = MFMA(ah0, bh1, acc[0][1]); acc[0][1] = MFMA(ah0, bl1, acc[0][1]); acc[0][1] = MFMA(al0, bh1, acc[0][1]);
            acc[1][0] = MFMA(ah1, bh0, acc[1][0]); acc[1][0] = MFMA(ah1, bl0, acc[1][0]); acc[1][0] = MFMA(al1, bh0, acc[1][0]);
            acc[1][1] = MFMA(ah1, bh1, acc[1][1]); acc[1][1] = MFMA(ah1, bl1, acc[1][1]); acc[1][1] = MFMA(al1, bh1, acc[1][1]);
        }
    }
    #pragma unroll
    for (int mi = 0; mi < 2; ++mi)
      #pragma unroll
      for (int ni = 0; ni < 2; ++ni)
        #pragma unroll
        for (int r = 0; r < 4; ++r) {
            int row = m0 + wm*32 + mi*16 + l4*4 + r;
            if (row < M) {
                int col = n0 + wn*32 + ni*16 + l15;
                float v = acc[mi][ni][r];
                u16 h = f2bf(v);
                Chi[(size_t)row * D + col] = h;
                Clo[(size_t)row * D + col] = f2bf(v - bf2f(h));
            }
        }
}

// In-place L2 row-normalize of a bf16 hi/lo pair (row = hi+lo, renormalize, resplit).
__global__ __launch_bounds__(128)
void l2norm_resplit_k(u16* __restrict__ hi, u16* __restrict__ lo) {
    const int row = blockIdx.x, tid = threadIdx.x;
    const size_t base = (size_t)row * D + tid * 4;
    short4v hv = *(short4v*)&hi[base], lv = *(short4v*)&lo[base];
    float v[4]; float ss = 0.f;
    #pragma unroll
    for (int j = 0; j < 4; ++j) {
        v[j] = bf2f((u16)hv[j]) + bf2f((u16)lv[j]);
        ss += v[j] * v[j];
    }
    ss = wave_reduce_sum(ss);
    __shared__ float red[2];
    if ((tid & 63) == 0) red[tid >> 6] = ss;
    __syncthreads();
    float inv = 1.0f / fmaxf(sqrtf(red[0] + red[1]), 1e-12f);
    short4v ho, lo_;
    #pragma unroll
    for (int j = 0; j < 4; ++j) {
        float y = v[j] * inv;
        u16 h = f2bf(y); ho[j] = (short)h; lo_[j] = (short)f2bf(y - bf2f(h));
    }
    *(short4v*)&hi[base] = ho; *(short4v*)&lo[base] = lo_;
}

// ecr[row][lab] = (l1norm(ex_classes[row]) @ class_reps)[lab]; padded to LABP with zeros.
__global__ __launch_bounds__(128)
void ecr_k(const float* __restrict__ exc, const float* __restrict__ creps,
           float* __restrict__ ecr) {
    const int row = blockIdx.x, tid = threadIdx.x;
    __shared__ float aL[N_LAB];
    __shared__ float red[2];
    float v = 0.f;
    if (tid < N_LAB) { v = exc[(size_t)row * N_LAB + tid]; aL[tid] = v; }
    float s = wave_reduce_sum(fabsf(v));
    if ((tid & 63) == 0) red[tid >> 6] = s;
    __syncthreads();
    float inv = 1.0f / fmaxf(red[0] + red[1], 1e-12f);
    if (tid < LABP) {
        float acc = 0.f;
        if (tid < N_LAB) {
            for (int c = 0; c < N_LAB; ++c) acc += aL[c] * creps[c * N_LAB + tid];
            acc *= inv;
        }
        ecr[(size_t)row * LABP + tid] = acc;
    }
}

// ecr_t[lab][e] (bf16 hi/lo), e padded to EXP with zeros.
__global__ __launch_bounds__(256)
void ecr_tsplit_k(const float* __restrict__ ecr, u16* __restrict__ th, u16* __restrict__ tl) {
    int e = blockIdx.x * 256 + threadIdx.x;
    int lab = blockIdx.y;
    if (e >= EXP) return;
    float v = (e < N_EX) ? ecr[(size_t)e * LABP + lab] : 0.f;
    u16 h = f2bf(v);
    th[(size_t)lab * EXP + e] = h;
    tl[(size_t)lab * EXP + e] = f2bf(v - bf2f(h));
}

// Fused: s = fn @ en^T (3-pass split MFMA), cube, den += |s^3|, num += s^3 @ ecr (3-pass MFMA).
__global__ __launch_bounds__(256, 2)
void fused_k(const u16* __restrict__ fnh, const u16* __restrict__ fnl,
             const u16* __restrict__ enh, const u16* __restrict__ enl,
             const u16* __restrict__ ecth, const u16* __restrict__ ectl,
             float* __restrict__ nump, float* __restrict__ denp) {
    __shared__ u16 AH[64][72], AL[64][72], BH[64][72], BL[64][72];
    __shared__ float denL[64][2];
    const int tid = threadIdx.x;
    const int lane = tid & 63, wave = tid >> 6;
    const int wm = wave >> 1, wn = wave & 1;
    const int l15 = lane & 15, l4 = lane >> 4;
    const int m0 = blockIdx.x * 64;
    const int split = blockIdx.y;

    f32x4 num_acc[7] = {};
    float den_th[2][4] = {};

    for (int t = split; t < NT; t += SPLITS) {
        const int e0 = t * 64;
        f32x4 sacc[2][2] = {};
        for (int kc = 0; kc < 8; ++kc) {
            __syncthreads();
            #pragma unroll
            for (int s = 0; s < 2; ++s) {
                int ix = tid + s * 256;
                int r = ix >> 3, c = ix & 7;
                const size_t ao = (size_t)(m0 + r) * D + kc * 64 + c * 8;
                *(short8v*)&AH[r][c*8] = *(const short8v*)&fnh[ao];
                *(short8v*)&AL[r][c*8] = *(const short8v*)&fnl[ao];
                short8v bh = {0,0,0,0,0,0,0,0}, bl = {0,0,0,0,0,0,0,0};
                if (e0 + r < N_EX) {
                    const size_t bo = (size_t)(e0 + r) * D + kc * 64 + c * 8;
                    bh = *(const short8v*)&enh[bo];
                    bl = *(const short8v*)&enl[bo];
                }
                *(short8v*)&BH[r][c*8] = bh;
                *(short8v*)&BL[r][c*8] = bl;
            }
            __syncthreads();
            #pragma unroll
            for (int ks = 0; ks < 2; ++ks) {
                const int ko = ks * 32 + l4 * 8;
                short8v ah0 = *(const short8v*)&AH[wm*32      + l15][ko];
                short8v ah1 = *(const short8v*)&AH[wm*32 + 16 + l15][ko];
                short8v al0 = *(const short8v*)&AL[wm*32      + l15][ko];
                short8v al1 = *(const short8v*)&AL[wm*32 + 16 + l15][ko];
                short8v bh0 = *(const short8v*)&BH[wn*32      + l15][ko];
                short8v bh1 = *(const short8v*)&BH[wn*32 + 16 + l15][ko];
                short8v bl0 = *(const short8v*)&BL[wn*32      + l15][ko];
                short8v bl1 = *(const short8v*)&BL[wn*32 + 16 + l15][ko];
                sacc[0][0] = MFMA(ah0, bh0, sacc[0][0]); sacc[0][0] = MFMA(ah0, bl0, sacc[0][0]); sacc[0][0] = MFMA(al0, bh0, sacc[0][0]);
                sacc[0][1] = MFMA(ah0, bh1, sacc[0][1]); sacc[0][1] = MFMA(ah0, bl1, sacc[0][1]); sacc[0][1] = MFMA(al0, bh1, sacc[0][1]);
                sacc[1][0] = MFMA(ah1, bh0, sacc[1][0]); sacc[1][0] = MFMA(ah1, bl0, sacc[1][0]); sacc[1][0] = MFMA(al1, bh0, sacc[1][0]);
                sacc[1][1] = MFMA(ah1, bh1, sacc[1][1]); sacc[1][1] = MFMA(ah1, bl1, sacc[1][1]); sacc[1][1] = MFMA(al1, bh1, sacc[1][1]);
            }
        }
        __syncthreads();   // all waves done reading A/B tiles
        // cube accumulators, track den, deposit a3 (bf16 hi/lo) into AH/AL
        #pragma unroll
        for (int mi = 0; mi < 2; ++mi)
          #pragma unroll
          for (int ni = 0; ni < 2; ++ni)
            #pragma unroll
            for (int r = 0; r < 4; ++r) {
                float sv = sacc[mi][ni][r];
                float a3 = sv * sv * sv;
                den_th[mi][r] += fabsf(a3);
                int row = wm*32 + mi*16 + l4*4 + r;
                int col = wn*32 + ni*16 + l15;
                u16 h = f2bf(a3);
                AH[row][col] = h;
                AL[row][col] = f2bf(a3 - bf2f(h));
            }
        __syncthreads();
        // num += a3 @ ecr_tile (A from LDS, B fragments straight from L2/L3-resident ecr_t)
        #pragma unroll
        for (int ks = 0; ks < 2; ++ks) {
            const int eo = ks * 32 + l4 * 8;
            short8v ph = *(const short8v*)&AH[wave*16 + l15][eo];
            short8v pl = *(const short8v*)&AL[wave*16 + l15][eo];
            #pragma unroll
            for (int ni = 0; ni < 7; ++ni) {
                const size_t wr = (size_t)(ni*16 + l15) * EXP + e0 + eo;
                short8v wh = *(const short8v*)&ecth[wr];
                short8v wl = *(const short8v*)&ectl[wr];
                num_acc[ni] = MFMA(ph, wh, num_acc[ni]);
                num_acc[ni] = MFMA(pl, wh, num_acc[ni]);
                num_acc[ni] = MFMA(ph, wl, num_acc[ni]);
            }
        }
    }
    // den: reduce over the 16 lanes sharing rows, then across the two wn waves
    #pragma unroll
    for (int mi = 0; mi < 2; ++mi)
      #pragma unroll
      for (int r = 0; r < 4; ++r) {
        float dv = den_th[mi][r];
        dv += __shfl_xor(dv, 1); dv += __shfl_xor(dv, 2);
        dv += __shfl_xor(dv, 4); dv += __shfl_xor(dv, 8);
        den_th[mi][r] = dv;
      }
    if (l15 == 0) {
        #pragma unroll
        for (int mi = 0; mi < 2; ++mi)
          #pragma unroll
          for (int r = 0; r < 4; ++r)
            denL[wm*32 + mi*16 + l4*4 + r][wn] = den_th[mi][r];
    }
    __syncthreads();
    if (tid < 64)
        denp[(size_t)split * B_ROWS + m0 + tid] = denL[tid][0] + denL[tid][1];
    #pragma unroll
    for (int ni = 0; ni < 7; ++ni)
      #pragma unroll
      for (int r = 0; r < 4; ++r)
        nump[((size_t)split * B_ROWS + m0 + wave*16 + l4*4 + r) * LABP + ni*16 + l15] = num_acc[ni][r];
}

// echo[row][lab] = sum_s num[s][row][lab] / max(sum_s den[s][row], eps)
__global__ __launch_bounds__(128)
void finalize_k(const float* __restrict__ nump, const float* __restrict__ denp,
                float* __restrict__ out) {
    const int row = blockIdx.x, tid = threadIdx.x;
    float den = 0.f;
    #pragma unroll
    for (int s = 0; s < SPLITS; ++s) den += denp[(size_t)s * B_ROWS + row];
    if (tid < N_LAB) {
        float acc = 0.f;
        #pragma unroll
        for (int s = 0; s < SPLITS; ++s) acc += nump[((size_t)s * B_ROWS + row) * LABP + tid];
        out[(size_t)row * N_LAB + tid] = acc / fmaxf(den, 1e-12f);
    }
}

extern "C" void kernel_launch(void* const* d_in, const int* in_sizes, int n_in,
                              void* d_out, int out_size, void* d_ws, size_t ws_size,
                              hipStream_t stream) {
    (void)in_sizes; (void)n_in; (void)out_size; (void)ws_size;
    const float* features    = (const float*)d_in[0];
    const float* g_weight    = (const float*)d_in[1];
    const float* ex_features = (const float*)d_in[2];
    const float* ex_classes  = (const float*)d_in[3];
    const float* class_reps  = (const float*)d_in[4];
    float* out = (float*)d_out;

    // Workspace layout (~82.1 MB), all segments 16B-aligned
    char* w = (char*)d_ws;
    u16* fnh = (u16*)w;      w += (size_t)B_ROWS * D * 2;
    u16* fnl = (u16*)w;      w += (size_t)B_ROWS * D * 2;
    u16* enh = (u16*)w;      w += (size_t)N_EX * D * 2;
    u16* enl = (u16*)w;      w += (size_t)N_EX * D * 2;
    float* ecr = (float*)w;  w += (size_t)N_EX * LABP * 4;
    u16* ecth = (u16*)w;     w += (size_t)LABP * EXP * 2;
    u16* ectl = (u16*)w;     w += (size_t)LABP * EXP * 2;
    float* nump = (float*)w; w += (size_t)SPLITS * B_ROWS * LABP * 4;
    float* denp = (float*)w;

    proj_k<<<dim3(B_ROWS / 64, 8), 256, 0, stream>>>(features, g_weight, fnh, fnl, B_ROWS);
    proj_k<<<dim3((N_EX + 63) / 64, 8), 256, 0, stream>>>(ex_features, g_weight, enh, enl, N_EX);
    l2norm_resplit_k<<<B_ROWS, 128, 0, stream>>>(fnh, fnl);
    l2norm_resplit_k<<<N_EX, 128, 0, stream>>>(enh, enl);
    ecr_k<<<N_EX, 128, 0, stream>>>(ex_classes, class_reps, ecr);
    ecr_tsplit_k<<<dim3((EXP + 255) / 256, LABP), 256, 0, stream>>>(ecr, ecth, ectl);
    fused_k<<<dim3(B_ROWS / 64, SPLITS), 256, 0, stream>>>(fnh, fnl, enh, enl, ecth, ectl, nump, denp);
    finalize_k<<<B_ROWS, 128, 0, stream>>>(nump, denp, out);
}

// Round 3
// 622.127 us; speedup vs baseline: 9.9758x; 1.3032x over previous
//
#include <hip/hip_runtime.h>

#define B_ROWS 4096
#define D      512
#define N_EX   20000
#define EXP2   20096     // N_EX padded to multiple of 128
#define N_LAB  100
#define LABP   112       // labels padded to 7x16
#define NT2    157       // EXP2 / 128

typedef __attribute__((ext_vector_type(8)))  short short8v;   // 8 bf16 (MFMA A/B frag)
typedef __attribute__((ext_vector_type(4)))  short short4v;
typedef __attribute__((ext_vector_type(4)))  float f32x4;
typedef __attribute__((ext_vector_type(16))) float f32x16;
typedef unsigned short u16;

__device__ __forceinline__ u16 f2bf(float x) {
    unsigned u = __builtin_bit_cast(unsigned, x);
    u = u + 0x7FFFu + ((u >> 16) & 1u);          // RNE
    return (u16)(u >> 16);
}
__device__ __forceinline__ float bf2f(u16 h) {
    unsigned u = ((unsigned)h) << 16;
    return __builtin_bit_cast(float, u);
}

__device__ __forceinline__ float wave_reduce_sum(float v) {
    #pragma unroll
    for (int off = 32; off > 0; off >>= 1) v += __shfl_down(v, off, 64);
    return v;
}

__device__ __forceinline__ void gload16(const void* g, void* l) {
    __builtin_amdgcn_global_load_lds((const __attribute__((address_space(1))) void*)g,
                                     (__attribute__((address_space(3))) void*)l, 16, 0, 0);
}

#define MFMA16(a, b, c) __builtin_amdgcn_mfma_f32_16x16x32_bf16((a), (b), (c), 0, 0, 0)
#define MFMA32(a, b, c) __builtin_amdgcn_mfma_f32_32x32x16_bf16((a), (b), (c), 0, 0, 0)

// ---------------- projection: C = X @ W^T (3-pass split-bf16), bf16 hi/lo out ----------------
__global__ __launch_bounds__(256, 2)
void proj_k(const float* __restrict__ X, const float* __restrict__ W,
            u16* __restrict__ Chi, u16* __restrict__ Clo, int M) {
    __shared__ u16 AH[64][72], AL[64][72], BH[64][72], BL[64][72];
    const int tid = threadIdx.x;
    const int lane = tid & 63, wave = tid >> 6;
    const int wm = wave >> 1, wn = wave & 1;
    const int l15 = lane & 15, l4 = lane >> 4;
    const int m0 = blockIdx.x * 64, n0 = blockIdx.y * 64;
    f32x4 acc[2][2] = {};
    for (int kc = 0; kc < 8; ++kc) {
        __syncthreads();
        #pragma unroll
        for (int s = 0; s < 2; ++s) {
            int ix = tid + s * 256;
            int r = ix >> 3, c = ix & 7;
            float va[8] = {0.f,0.f,0.f,0.f,0.f,0.f,0.f,0.f};
            if (m0 + r < M) {
                const float* p = &X[(size_t)(m0 + r) * D + kc * 64 + c * 8];
                float4 t0 = *(const float4*)p, t1 = *(const float4*)(p + 4);
                va[0]=t0.x; va[1]=t0.y; va[2]=t0.z; va[3]=t0.w;
                va[4]=t1.x; va[5]=t1.y; va[6]=t1.z; va[7]=t1.w;
            }
            short8v h, l;
            #pragma unroll
            for (int j = 0; j < 8; ++j) {
                u16 hh = f2bf(va[j]); h[j] = (short)hh; l[j] = (short)f2bf(va[j] - bf2f(hh));
            }
            *(short8v*)&AH[r][c*8] = h; *(short8v*)&AL[r][c*8] = l;
            const float* q = &W[(size_t)(n0 + r) * D + kc * 64 + c * 8];
            float4 s0 = *(const float4*)q, s1 = *(const float4*)(q + 4);
            float vb[8] = {s0.x,s0.y,s0.z,s0.w,s1.x,s1.y,s1.z,s1.w};
            #pragma unroll
            for (int j = 0; j < 8; ++j) {
                u16 hh = f2bf(vb[j]); h[j] = (short)hh; l[j] = (short)f2bf(vb[j] - bf2f(hh));
            }
            *(short8v*)&BH[r][c*8] = h; *(short8v*)&BL[r][c*8] = l;
        }
        __syncthreads();
        #pragma unroll
        for (int ks = 0; ks < 2; ++ks) {
            const int ko = ks * 32 + l4 * 8;
            short8v ah0 = *(const short8v*)&AH[wm*32      + l15][ko];
            short8v ah1 = *(const short8v*)&AH[wm*32 + 16 + l15][ko];
            short8v al0 = *(const short8v*)&AL[wm*32      + l15][ko];
            short8v al1 = *(const short8v*)&AL[wm*32 + 16 + l15][ko];
            short8v bh0 = *(const short8v*)&BH[wn*32      + l15][ko];
            short8v bh1 = *(const short8v*)&BH[wn*32 + 16 + l15][ko];
            short8v bl0 = *(const short8v*)&BL[wn*32      + l15][ko];
            short8v bl1 = *(const short8v*)&BL[wn*32 + 16 + l15][ko];
            acc[0][0] = MFMA16(ah0, bh0, acc[0][0]); acc[0][0] = MFMA16(ah0, bl0, acc[0][0]); acc[0][0] = MFMA16(al0, bh0, acc[0][0]);
            acc[0][1] = MFMA16(ah0, bh1, acc[0][1]); acc[0][1] = MFMA16(ah0, bl1, acc[0][1]); acc[0][1] = MFMA16(al0, bh1, acc[0][1]);
            acc[1][0] = MFMA16(ah1, bh0, acc[1][0]); acc[1][0] = MFMA16(ah1, bl0, acc[1][0]); acc[1][0] = MFMA16(al1, bh0, acc[1][0]);
            acc[1][1] = MFMA16(ah1, bh1, acc[1][1]); acc[1][1] = MFMA16(ah1, bl1, acc[1][1]); acc[1][1] = MFMA16(al1, bh1, acc[1][1]);
        }
    }
    // store (pad rows beyond M get zeros since loads were zero-guarded)
    #pragma unroll
    for (int mi = 0; mi < 2; ++mi)
      #pragma unroll
      for (int ni = 0; ni < 2; ++ni)
        #pragma unroll
        for (int r = 0; r < 4; ++r) {
            int row = m0 + wm*32 + mi*16 + l4*4 + r;
            int col = n0 + wn*32 + ni*16 + l15;
            float v = acc[mi][ni][r];
            u16 h = f2bf(v);
            Chi[(size_t)row * D + col] = h;
            Clo[(size_t)row * D + col] = f2bf(v - bf2f(h));
        }
}

// ---------------- in-place L2 row-normalize of bf16 hi/lo pair ----------------
__global__ __launch_bounds__(128)
void l2norm_resplit_k(u16* __restrict__ hi, u16* __restrict__ lo) {
    const int row = blockIdx.x, tid = threadIdx.x;
    const size_t base = (size_t)row * D + tid * 4;
    short4v hv = *(short4v*)&hi[base], lv = *(short4v*)&lo[base];
    float v[4]; float ss = 0.f;
    #pragma unroll
    for (int j = 0; j < 4; ++j) {
        v[j] = bf2f((u16)hv[j]) + bf2f((u16)lv[j]);
        ss += v[j] * v[j];
    }
    ss = wave_reduce_sum(ss);
    __shared__ float red[2];
    if ((tid & 63) == 0) red[tid >> 6] = ss;
    __syncthreads();
    float inv = 1.0f / fmaxf(sqrtf(red[0] + red[1]), 1e-12f);
    short4v ho, lo_;
    #pragma unroll
    for (int j = 0; j < 4; ++j) {
        float y = v[j] * inv;
        u16 h = f2bf(y); ho[j] = (short)h; lo_[j] = (short)f2bf(y - bf2f(h));
    }
    *(short4v*)&hi[base] = ho; *(short4v*)&lo[base] = lo_;
}

// ---------------- ecr^T directly: th/tl[lab][e] = bf16 split of (l1norm(exc[e]) @ creps)[lab] ----------------
__global__ __launch_bounds__(128)
void ecrT_k(const float* __restrict__ exc, const float* __restrict__ creps,
            u16* __restrict__ th, u16* __restrict__ tl) {
    const int e = blockIdx.x, tid = threadIdx.x;
    if (e >= N_EX) {
        if (tid < LABP) { th[(size_t)tid * EXP2 + e] = 0; tl[(size_t)tid * EXP2 + e] = 0; }
        return;
    }
    __shared__ float aL[N_LAB];
    __shared__ float red[2];
    float v = 0.f;
    if (tid < N_LAB) { v = exc[(size_t)e * N_LAB + tid]; aL[tid] = v; }
    float s = wave_reduce_sum(fabsf(v));
    if ((tid & 63) == 0) red[tid >> 6] = s;
    __syncthreads();
    float inv = 1.0f / fmaxf(red[0] + red[1], 1e-12f);
    if (tid < LABP) {
        float acc = 0.f;
        if (tid < N_LAB) {
            for (int c = 0; c < N_LAB; ++c) acc += aL[c] * creps[c * N_LAB + tid];
            acc *= inv;
        }
        u16 h = f2bf(acc);
        th[(size_t)tid * EXP2 + e] = h;
        tl[(size_t)tid * EXP2 + e] = f2bf(acc - bf2f(h));
    }
}

// ---------------- fused main: s = fn@en^T (32x32x16, 3-pass), cube, den, num = a3@ecr (16x16x32, 3-pass) ----------------
__global__ __launch_bounds__(256, 2)
void fused_k(const u16* __restrict__ fnh, const u16* __restrict__ fnl,
             const u16* __restrict__ enh, const u16* __restrict__ enl,
             const u16* __restrict__ ecth, const u16* __restrict__ ectl,
             float* __restrict__ nump, float* __restrict__ denp2, int splits) {
    // 64 KiB: staging A/B hi/lo [128][64] u16 (linear rows, XOR-swizzled source);
    // reused in epilogue as a3 hi [128][128] (SM[0..1]) and a3 lo (SM[2..3]).
    __shared__ u16 SM[4][128][64];
    u16* a3h = &SM[0][0][0];
    u16* a3l = &SM[2][0][0];

    const int tid = threadIdx.x;
    const int l = tid & 63, w = tid >> 6;
    const int wm = w >> 1, wn = w & 1;
    const int l31 = l & 31, l5 = l >> 5;
    const int l15 = l & 15, l4 = l >> 4;       // 16x16 frag: k-group = l>>4 (0..3)
    const int m0 = blockIdx.x * 128;
    const int split = blockIdx.y;

    const int r_in = l >> 3;                   // staging: row within 8-row chunk
    const int c16s = (l & 7) ^ r_in;           // pre-swizzled source chunk

    f32x4 num_acc[2][7] = {};
    float den_acc[2][16] = {};

    for (int t = split; t < NT2; t += splits) {
        const int e0 = t * 128;
        f32x16 sacc[2][2] = {};
        for (int kc = 0; kc < 8; ++kc) {
            __syncthreads();                   // prior LDS reads done
            const int kofs = kc * 64;
            #pragma unroll
            for (int i = 0; i < 4; ++i) {
                const int q = w * 4 + i;       // 16 chunks of 8 rows
                const int row = q * 8 + r_in;
                const size_t fo = (size_t)(m0 + row) * D + kofs + c16s * 8;
                const size_t eo_ = (size_t)(e0 + row) * D + kofs + c16s * 8;
                gload16(&fnh[fo], (u16*)&SM[0][0][0] + q * 512);
                gload16(&fnl[fo], (u16*)&SM[1][0][0] + q * 512);
                gload16(&enh[eo_], (u16*)&SM[2][0][0] + q * 512);
                gload16(&enl[eo_], (u16*)&SM[3][0][0] + q * 512);
            }
            __syncthreads();                   // vmcnt(0) drained here
            #pragma unroll
            for (int ks = 0; ks < 4; ++ks) {
                short8v ah[2], al[2], bh[2], bl[2];
                #pragma unroll
                for (int mi = 0; mi < 2; ++mi) {
                    int row = wm * 64 + mi * 32 + l31;
                    int cc = ((ks * 2 + l5) ^ (row & 7)) * 8;
                    ah[mi] = *(const short8v*)&SM[0][row][cc];
                    al[mi] = *(const short8v*)&SM[1][row][cc];
                }
                #pragma unroll
                for (int ni = 0; ni < 2; ++ni) {
                    int row = wn * 64 + ni * 32 + l31;
                    int cc = ((ks * 2 + l5) ^ (row & 7)) * 8;
                    bh[ni] = *(const short8v*)&SM[2][row][cc];
                    bl[ni] = *(const short8v*)&SM[3][row][cc];
                }
                #pragma unroll
                for (int mi = 0; mi < 2; ++mi)
                    #pragma unroll
                    for (int ni = 0; ni < 2; ++ni) {
                        sacc[mi][ni] = MFMA32(ah[mi], bh[ni], sacc[mi][ni]);
                        sacc[mi][ni] = MFMA32(ah[mi], bl[ni], sacc[mi][ni]);
                        sacc[mi][ni] = MFMA32(al[mi], bh[ni], sacc[mi][ni]);
                    }
            }
        }
        __syncthreads();                       // all waves done reading staged A/B
        // cube + den + deposit a3 (bf16 hi/lo) into swizzled [128][128] LDS
        #pragma unroll
        for (int mi = 0; mi < 2; ++mi)
          #pragma unroll
          for (int ni = 0; ni < 2; ++ni)
            #pragma unroll
            for (int r = 0; r < 16; ++r) {
                float sv = sacc[mi][ni][r];
                float a3 = sv * sv * sv;
                den_acc[mi][r] += fabsf(a3);
                int row = wm * 64 + mi * 32 + (r & 3) + 8 * (r >> 2) + 4 * l5;
                int col = wn * 64 + ni * 32 + l31;
                int idx = row * 128 + (((col >> 3) ^ (row & 7)) * 8) + (col & 7);
                u16 h = f2bf(a3);
                a3h[idx] = h;
                a3l[idx] = f2bf(a3 - bf2f(h));
            }
        __syncthreads();                       // deposits visible
        // num += a3 @ ecr_tile (A from LDS, B straight from L2/L3-resident ecr_t)
        #pragma unroll
        for (int eo = 0; eo < 4; ++eo) {
            short8v ph[2], pl[2];
            #pragma unroll
            for (int mi2 = 0; mi2 < 2; ++mi2) {
                int row = w * 32 + mi2 * 16 + l15;
                int cc = ((eo * 4 + l4) ^ (row & 7)) * 8;
                ph[mi2] = *(const short8v*)&a3h[row * 128 + cc];
                pl[mi2] = *(const short8v*)&a3l[row * 128 + cc];
            }
            #pragma unroll
            for (int ni = 0; ni < 7; ++ni) {
                const size_t wr = (size_t)(ni * 16 + l15) * EXP2 + e0 + eo * 32 + l4 * 8;
                short8v whv = *(const short8v*)&ecth[wr];
                short8v wlv = *(const short8v*)&ectl[wr];
                #pragma unroll
                for (int mi2 = 0; mi2 < 2; ++mi2) {
                    num_acc[mi2][ni] = MFMA16(ph[mi2], whv, num_acc[mi2][ni]);
                    num_acc[mi2][ni] = MFMA16(pl[mi2], whv, num_acc[mi2][ni]);
                    num_acc[mi2][ni] = MFMA16(ph[mi2], wlv, num_acc[mi2][ni]);
                }
            }
        }
    }
    // den: reduce across the 32 lanes of each half-wave, write per-(split, wn) partials
    #pragma unroll
    for (int mi = 0; mi < 2; ++mi)
      #pragma unroll
      for (int r = 0; r < 16; ++r) {
        float v = den_acc[mi][r];
        v += __shfl_xor(v, 1);  v += __shfl_xor(v, 2);  v += __shfl_xor(v, 4);
        v += __shfl_xor(v, 8);  v += __shfl_xor(v, 16);
        if (l31 == 0) {
            int row = wm * 64 + mi * 32 + (r & 3) + 8 * (r >> 2) + 4 * l5;
            denp2[((size_t)split * 2 + wn) * B_ROWS + m0 + row] = v;
        }
      }
    // num partials
    #pragma unroll
    for (int mi2 = 0; mi2 < 2; ++mi2)
      #pragma unroll
      for (int ni = 0; ni < 7; ++ni)
        #pragma unroll
        for (int r = 0; r < 4; ++r) {
            int grow = m0 + w * 32 + mi2 * 16 + l4 * 4 + r;
            nump[((size_t)split * B_ROWS + grow) * LABP + ni * 16 + l15] = num_acc[mi2][ni][r];
        }
}

// ---------------- finalize ----------------
__global__ __launch_bounds__(128)
void finalize_k(const float* __restrict__ nump, const float* __restrict__ denp2,
                float* __restrict__ out, int splits) {
    const int row = blockIdx.x, tid = threadIdx.x;
    float den = 0.f;
    for (int s = 0; s < splits; ++s)
        den += denp2[((size_t)s * 2 + 0) * B_ROWS + row] + denp2[((size_t)s * 2 + 1) * B_ROWS + row];
    if (tid < N_LAB) {
        float acc = 0.f;
        for (int s = 0; s < splits; ++s)
            acc += nump[((size_t)s * B_ROWS + row) * LABP + tid];
        out[(size_t)row * N_LAB + tid] = acc / fmaxf(den, 1e-12f);
    }
}

extern "C" void kernel_launch(void* const* d_in, const int* in_sizes, int n_in,
                              void* d_out, int out_size, void* d_ws, size_t ws_size,
                              hipStream_t stream) {
    (void)in_sizes; (void)n_in; (void)out_size;
    const float* features    = (const float*)d_in[0];
    const float* g_weight    = (const float*)d_in[1];
    const float* ex_features = (const float*)d_in[2];
    const float* ex_classes  = (const float*)d_in[3];
    const float* class_reps  = (const float*)d_in[4];
    float* out = (float*)d_out;

    // workspace layout (256B-aligned segments)
    size_t off = 0;
    auto alloc = [&](size_t bytes) {
        void* p = (char*)d_ws + off;
        off += (bytes + 255) & ~(size_t)255;
        return p;
    };
    u16* fnh = (u16*)alloc((size_t)B_ROWS * D * 2);
    u16* fnl = (u16*)alloc((size_t)B_ROWS * D * 2);
    u16* enh = (u16*)alloc((size_t)EXP2 * D * 2);
    u16* enl = (u16*)alloc((size_t)EXP2 * D * 2);
    u16* ecth = (u16*)alloc((size_t)LABP * EXP2 * 2);
    u16* ectl = (u16*)alloc((size_t)LABP * EXP2 * 2);
    // pick split count based on remaining workspace
    size_t rem = ws_size - off;
    int splits = 16;
    size_t need16 = (size_t)16 * B_ROWS * LABP * 4 + (size_t)16 * 2 * B_ROWS * 4 + 1024;
    if (rem < need16) splits = 8;
    float* nump  = (float*)alloc((size_t)splits * B_ROWS * LABP * 4);
    float* denp2 = (float*)alloc((size_t)splits * 2 * B_ROWS * 4);

    proj_k<<<dim3(B_ROWS / 64, 8), 256, 0, stream>>>(features, g_weight, fnh, fnl, B_ROWS);
    proj_k<<<dim3(EXP2 / 64, 8), 256, 0, stream>>>(ex_features, g_weight, enh, enl, N_EX);
    l2norm_resplit_k<<<B_ROWS, 128, 0, stream>>>(fnh, fnl);
    l2norm_resplit_k<<<EXP2, 128, 0, stream>>>(enh, enl);
    ecrT_k<<<EXP2, 128, 0, stream>>>(ex_classes, class_reps, ecth, ectl);
    fused_k<<<dim3(B_ROWS / 128, splits), 256, 0, stream>>>(fnh, fnl, enh, enl, ecth, ectl, nump, denp2, splits);
    finalize_k<<<B_ROWS, 128, 0, stream>>>(nump, denp2, out, splits);
}

// Round 4
// 556.711 us; speedup vs baseline: 11.1480x; 1.1175x over previous
//
#include <hip/hip_runtime.h>

#define B_ROWS 4096
#define D      512
#define N_EX   20000
#define EXP2   20096     // N_EX padded to multiple of 128
#define N_LAB  100
#define LABP   112       // labels padded to 7x16
#define NT2    157       // EXP2 / 128

typedef __attribute__((ext_vector_type(8)))  short short8v;   // 8 bf16 (MFMA A/B frag)
typedef __attribute__((ext_vector_type(4)))  short short4v;
typedef __attribute__((ext_vector_type(4)))  float f32x4;
typedef __attribute__((ext_vector_type(16))) float f32x16;
typedef unsigned short u16;

__device__ __forceinline__ u16 f2bf(float x) {
    unsigned u = __builtin_bit_cast(unsigned, x);
    u = u + 0x7FFFu + ((u >> 16) & 1u);          // RNE
    return (u16)(u >> 16);
}
__device__ __forceinline__ float bf2f(u16 h) {
    unsigned u = ((unsigned)h) << 16;
    return __builtin_bit_cast(float, u);
}

__device__ __forceinline__ float wave_reduce_sum(float v) {
    #pragma unroll
    for (int off = 32; off > 0; off >>= 1) v += __shfl_down(v, off, 64);
    return v;
}

__device__ __forceinline__ void gload16(const void* g, void* l) {
    __builtin_amdgcn_global_load_lds((const __attribute__((address_space(1))) void*)g,
                                     (__attribute__((address_space(3))) void*)l, 16, 0, 0);
}

#define MFMA16(a, b, c) __builtin_amdgcn_mfma_f32_16x16x32_bf16((a), (b), (c), 0, 0, 0)
#define MFMA32(a, b, c) __builtin_amdgcn_mfma_f32_32x32x16_bf16((a), (b), (c), 0, 0, 0)

// ---------------- projection: C = X @ W^T (3-pass split-bf16), bf16 hi/lo out ----------------
__global__ __launch_bounds__(256, 2)
void proj_k(const float* __restrict__ X, const float* __restrict__ W,
            u16* __restrict__ Chi, u16* __restrict__ Clo, int M) {
    __shared__ u16 AH[64][72], AL[64][72], BH[64][72], BL[64][72];
    const int tid = threadIdx.x;
    const int lane = tid & 63, wave = tid >> 6;
    const int wm = wave >> 1, wn = wave & 1;
    const int l15 = lane & 15, l4 = lane >> 4;
    const int m0 = blockIdx.x * 64, n0 = blockIdx.y * 64;
    f32x4 acc[2][2] = {};
    for (int kc = 0; kc < 8; ++kc) {
        __syncthreads();
        #pragma unroll
        for (int s = 0; s < 2; ++s) {
            int ix = tid + s * 256;
            int r = ix >> 3, c = ix & 7;
            float va[8] = {0.f,0.f,0.f,0.f,0.f,0.f,0.f,0.f};
            if (m0 + r < M) {
                const float* p = &X[(size_t)(m0 + r) * D + kc * 64 + c * 8];
                float4 t0 = *(const float4*)p, t1 = *(const float4*)(p + 4);
                va[0]=t0.x; va[1]=t0.y; va[2]=t0.z; va[3]=t0.w;
                va[4]=t1.x; va[5]=t1.y; va[6]=t1.z; va[7]=t1.w;
            }
            short8v h, l;
            #pragma unroll
            for (int j = 0; j < 8; ++j) {
                u16 hh = f2bf(va[j]); h[j] = (short)hh; l[j] = (short)f2bf(va[j] - bf2f(hh));
            }
            *(short8v*)&AH[r][c*8] = h; *(short8v*)&AL[r][c*8] = l;
            const float* q = &W[(size_t)(n0 + r) * D + kc * 64 + c * 8];
            float4 s0 = *(const float4*)q, s1 = *(const float4*)(q + 4);
            float vb[8] = {s0.x,s0.y,s0.z,s0.w,s1.x,s1.y,s1.z,s1.w};
            #pragma unroll
            for (int j = 0; j < 8; ++j) {
                u16 hh = f2bf(vb[j]); h[j] = (short)hh; l[j] = (short)f2bf(vb[j] - bf2f(hh));
            }
            *(short8v*)&BH[r][c*8] = h; *(short8v*)&BL[r][c*8] = l;
        }
        __syncthreads();
        #pragma unroll
        for (int ks = 0; ks < 2; ++ks) {
            const int ko = ks * 32 + l4 * 8;
            short8v ah0 = *(const short8v*)&AH[wm*32      + l15][ko];
            short8v ah1 = *(const short8v*)&AH[wm*32 + 16 + l15][ko];
            short8v al0 = *(const short8v*)&AL[wm*32      + l15][ko];
            short8v al1 = *(const short8v*)&AL[wm*32 + 16 + l15][ko];
            short8v bh0 = *(const short8v*)&BH[wn*32      + l15][ko];
            short8v bh1 = *(const short8v*)&BH[wn*32 + 16 + l15][ko];
            short8v bl0 = *(const short8v*)&BL[wn*32      + l15][ko];
            short8v bl1 = *(const short8v*)&BL[wn*32 + 16 + l15][ko];
            acc[0][0] = MFMA16(ah0, bh0, acc[0][0]); acc[0][0] = MFMA16(ah0, bl0, acc[0][0]); acc[0][0] = MFMA16(al0, bh0, acc[0][0]);
            acc[0][1] = MFMA16(ah0, bh1, acc[0][1]); acc[0][1] = MFMA16(ah0, bl1, acc[0][1]); acc[0][1] = MFMA16(al0, bh1, acc[0][1]);
            acc[1][0] = MFMA16(ah1, bh0, acc[1][0]); acc[1][0] = MFMA16(ah1, bl0, acc[1][0]); acc[1][0] = MFMA16(al1, bh0, acc[1][0]);
            acc[1][1] = MFMA16(ah1, bh1, acc[1][1]); acc[1][1] = MFMA16(ah1, bl1, acc[1][1]); acc[1][1] = MFMA16(al1, bh1, acc[1][1]);
        }
    }
    #pragma unroll
    for (int mi = 0; mi < 2; ++mi)
      #pragma unroll
      for (int ni = 0; ni < 2; ++ni)
        #pragma unroll
        for (int r = 0; r < 4; ++r) {
            int row = m0 + wm*32 + mi*16 + l4*4 + r;
            int col = n0 + wn*32 + ni*16 + l15;
            float v = acc[mi][ni][r];
            u16 h = f2bf(v);
            Chi[(size_t)row * D + col] = h;
            Clo[(size_t)row * D + col] = f2bf(v - bf2f(h));
        }
}

// ---------------- in-place L2 row-normalize of bf16 hi/lo pair ----------------
__global__ __launch_bounds__(128)
void l2norm_resplit_k(u16* __restrict__ hi, u16* __restrict__ lo) {
    const int row = blockIdx.x, tid = threadIdx.x;
    const size_t base = (size_t)row * D + tid * 4;
    short4v hv = *(short4v*)&hi[base], lv = *(short4v*)&lo[base];
    float v[4]; float ss = 0.f;
    #pragma unroll
    for (int j = 0; j < 4; ++j) {
        v[j] = bf2f((u16)hv[j]) + bf2f((u16)lv[j]);
        ss += v[j] * v[j];
    }
    ss = wave_reduce_sum(ss);
    __shared__ float red[2];
    if ((tid & 63) == 0) red[tid >> 6] = ss;
    __syncthreads();
    float inv = 1.0f / fmaxf(sqrtf(red[0] + red[1]), 1e-12f);
    short4v ho, lo_;
    #pragma unroll
    for (int j = 0; j < 4; ++j) {
        float y = v[j] * inv;
        u16 h = f2bf(y); ho[j] = (short)h; lo_[j] = (short)f2bf(y - bf2f(h));
    }
    *(short4v*)&hi[base] = ho; *(short4v*)&lo[base] = lo_;
}

// ---------------- ecr^T: th[lab][e] = bf16 of (l1norm(exc[e]) @ creps)[lab] ----------------
__global__ __launch_bounds__(128)
void ecrT_k(const float* __restrict__ exc, const float* __restrict__ creps,
            u16* __restrict__ th) {
    const int e = blockIdx.x, tid = threadIdx.x;
    if (e >= N_EX) {
        if (tid < LABP) th[(size_t)tid * EXP2 + e] = 0;
        return;
    }
    __shared__ float aL[N_LAB];
    __shared__ float red[2];
    float v = 0.f;
    if (tid < N_LAB) { v = exc[(size_t)e * N_LAB + tid]; aL[tid] = v; }
    float s = wave_reduce_sum(fabsf(v));
    if ((tid & 63) == 0) red[tid >> 6] = s;
    __syncthreads();
    float inv = 1.0f / fmaxf(red[0] + red[1], 1e-12f);
    if (tid < LABP) {
        float acc = 0.f;
        if (tid < N_LAB) {
            for (int c = 0; c < N_LAB; ++c) acc += aL[c] * creps[c * N_LAB + tid];
            acc *= inv;
        }
        th[(size_t)tid * EXP2 + e] = f2bf(acc);
    }
}

// ---------------- fused main ----------------
// s = fn@en^T (32x32x16, 3-pass split-bf16), cube, den, num = a3 @ ecr (16x16x32, 1-pass).
// ecr^T tile (112x128 bf16, 28KB) is DMA-staged into the freed B-region before the num phase.
__global__ __launch_bounds__(256, 2)
void fused_k(const u16* __restrict__ fnh, const u16* __restrict__ fnl,
             const u16* __restrict__ enh, const u16* __restrict__ enl,
             const u16* __restrict__ ecth,
             float* __restrict__ nump, float* __restrict__ denp2, int splits) {
    // 64 KiB staging: SM[0..1]=A hi/lo, SM[2..3]=B hi/lo (linear rows, XOR-swizzled source).
    // Epilogue reuse: SM[0..1] -> a3 hi [128][128]; SM[2..3] -> WT [112][128] (28KB).
    __shared__ u16 SM[4][128][64];
    u16* a3h = &SM[0][0][0];
    u16* WT  = &SM[2][0][0];

    const int tid = threadIdx.x;
    const int l = tid & 63, w = tid >> 6;
    const int wm = w >> 1, wn = w & 1;
    const int l31 = l & 31, l5 = l >> 5;
    const int l15 = l & 15, l4 = l >> 4;
    const int m0 = blockIdx.x * 128;
    const int split = blockIdx.y;

    const int r_in = l >> 3;                   // staging: row within 8-row chunk
    const int c16s = (l & 7) ^ r_in;           // pre-swizzled source chunk

    f32x4 num_acc[2][7] = {};
    float den_acc[2][16] = {};

    for (int t = split; t < NT2; t += splits) {
        const int e0 = t * 128;
        f32x16 sacc[2][2] = {};
        for (int kc = 0; kc < 8; ++kc) {
            __syncthreads();                   // prior LDS reads done
            const int kofs = kc * 64;
            #pragma unroll
            for (int i = 0; i < 4; ++i) {
                const int q = w * 4 + i;       // 16 chunks of 8 rows
                const int row = q * 8 + r_in;
                const size_t fo = (size_t)(m0 + row) * D + kofs + c16s * 8;
                const size_t eo_ = (size_t)(e0 + row) * D + kofs + c16s * 8;
                gload16(&fnh[fo], (u16*)&SM[0][0][0] + q * 512);
                gload16(&fnl[fo], (u16*)&SM[1][0][0] + q * 512);
                gload16(&enh[eo_], (u16*)&SM[2][0][0] + q * 512);
                gload16(&enl[eo_], (u16*)&SM[3][0][0] + q * 512);
            }
            __syncthreads();                   // vmcnt(0)+lgkm drained
            #pragma unroll
            for (int ks = 0; ks < 4; ++ks) {
                short8v ah[2], al[2], bh[2], bl[2];
                #pragma unroll
                for (int mi = 0; mi < 2; ++mi) {
                    int row = wm * 64 + mi * 32 + l31;
                    int cc = ((ks * 2 + l5) ^ (row & 7)) * 8;
                    ah[mi] = *(const short8v*)&SM[0][row][cc];
                    al[mi] = *(const short8v*)&SM[1][row][cc];
                }
                #pragma unroll
                for (int ni = 0; ni < 2; ++ni) {
                    int row = wn * 64 + ni * 32 + l31;
                    int cc = ((ks * 2 + l5) ^ (row & 7)) * 8;
                    bh[ni] = *(const short8v*)&SM[2][row][cc];
                    bl[ni] = *(const short8v*)&SM[3][row][cc];
                }
                #pragma unroll
                for (int mi = 0; mi < 2; ++mi)
                    #pragma unroll
                    for (int ni = 0; ni < 2; ++ni) {
                        sacc[mi][ni] = MFMA32(ah[mi], bh[ni], sacc[mi][ni]);
                        sacc[mi][ni] = MFMA32(ah[mi], bl[ni], sacc[mi][ni]);
                        sacc[mi][ni] = MFMA32(al[mi], bh[ni], sacc[mi][ni]);
                    }
            }
        }
        __syncthreads();                       // all waves done reading staged A/B
        // DMA-stage the ecr^T tile into the freed B-region (28KB), swizzled source.
        // row = p*16 + w*4 + (l>>4), ch = l&15 -> lane-linear dest = row*256B + ch*16B.
        #pragma unroll
        for (int p = 0; p < 7; ++p) {
            const int row = p * 16 + w * 4 + (l >> 4);
            const int ch = l & 15;
            gload16(&ecth[(size_t)row * EXP2 + e0 + ((ch ^ (row & 7)) * 8)],
                    WT + (p * 16 + w * 4) * 128);
        }
        // cube + den + deposit a3 hi into swizzled [128][128] LDS (overlaps the DMA latency)
        #pragma unroll
        for (int mi = 0; mi < 2; ++mi)
          #pragma unroll
          for (int ni = 0; ni < 2; ++ni)
            #pragma unroll
            for (int r = 0; r < 16; ++r) {
                float sv = sacc[mi][ni][r];
                float a3 = sv * sv * sv;
                den_acc[mi][r] += fabsf(a3);
                int row = wm * 64 + mi * 32 + (r & 3) + 8 * (r >> 2) + 4 * l5;
                int col = wn * 64 + ni * 32 + l31;
                a3h[row * 128 + (((col >> 3) ^ (row & 7)) * 8) + (col & 7)] = f2bf(a3);
            }
        __syncthreads();                       // deposits + WT DMA visible
        // num += a3 @ ecr_tile (1-pass bf16, all operands from LDS)
        #pragma unroll
        for (int eo = 0; eo < 4; ++eo) {
            short8v ph[2];
            #pragma unroll
            for (int mi2 = 0; mi2 < 2; ++mi2) {
                int row = w * 32 + mi2 * 16 + l15;
                int cc = ((eo * 4 + l4) ^ (row & 7)) * 8;
                ph[mi2] = *(const short8v*)&a3h[row * 128 + cc];
            }
            #pragma unroll
            for (int ni = 0; ni < 7; ++ni) {
                int row = ni * 16 + l15;
                int cc = ((eo * 4 + l4) ^ (row & 7)) * 8;
                short8v whv = *(const short8v*)&WT[row * 128 + cc];
                #pragma unroll
                for (int mi2 = 0; mi2 < 2; ++mi2)
                    num_acc[mi2][ni] = MFMA16(ph[mi2], whv, num_acc[mi2][ni]);
            }
        }
    }
    // den: reduce across the 32 lanes of each half-wave, write per-(split, wn) partials
    #pragma unroll
    for (int mi = 0; mi < 2; ++mi)
      #pragma unroll
      for (int r = 0; r < 16; ++r) {
        float v = den_acc[mi][r];
        v += __shfl_xor(v, 1);  v += __shfl_xor(v, 2);  v += __shfl_xor(v, 4);
        v += __shfl_xor(v, 8);  v += __shfl_xor(v, 16);
        if (l31 == 0) {
            int row = wm * 64 + mi * 32 + (r & 3) + 8 * (r >> 2) + 4 * l5;
            denp2[((size_t)split * 2 + wn) * B_ROWS + m0 + row] = v;
        }
      }
    // num partials
    #pragma unroll
    for (int mi2 = 0; mi2 < 2; ++mi2)
      #pragma unroll
      for (int ni = 0; ni < 7; ++ni)
        #pragma unroll
        for (int r = 0; r < 4; ++r) {
            int grow = m0 + w * 32 + mi2 * 16 + l4 * 4 + r;
            nump[((size_t)split * B_ROWS + grow) * LABP + ni * 16 + l15] = num_acc[mi2][ni][r];
        }
}

// ---------------- finalize ----------------
__global__ __launch_bounds__(128)
void finalize_k(const float* __restrict__ nump, const float* __restrict__ denp2,
                float* __restrict__ out, int splits) {
    const int row = blockIdx.x, tid = threadIdx.x;
    float den = 0.f;
    for (int s = 0; s < splits; ++s)
        den += denp2[((size_t)s * 2 + 0) * B_ROWS + row] + denp2[((size_t)s * 2 + 1) * B_ROWS + row];
    if (tid < N_LAB) {
        float acc = 0.f;
        for (int s = 0; s < splits; ++s)
            acc += nump[((size_t)s * B_ROWS + row) * LABP + tid];
        out[(size_t)row * N_LAB + tid] = acc / fmaxf(den, 1e-12f);
    }
}

extern "C" void kernel_launch(void* const* d_in, const int* in_sizes, int n_in,
                              void* d_out, int out_size, void* d_ws, size_t ws_size,
                              hipStream_t stream) {
    (void)in_sizes; (void)n_in; (void)out_size;
    const float* features    = (const float*)d_in[0];
    const float* g_weight    = (const float*)d_in[1];
    const float* ex_features = (const float*)d_in[2];
    const float* ex_classes  = (const float*)d_in[3];
    const float* class_reps  = (const float*)d_in[4];
    float* out = (float*)d_out;

    size_t off = 0;
    auto alloc = [&](size_t bytes) {
        void* p = (char*)d_ws + off;
        off += (bytes + 255) & ~(size_t)255;
        return p;
    };
    u16* fnh = (u16*)alloc((size_t)B_ROWS * D * 2);
    u16* fnl = (u16*)alloc((size_t)B_ROWS * D * 2);
    u16* enh = (u16*)alloc((size_t)EXP2 * D * 2);
    u16* enl = (u16*)alloc((size_t)EXP2 * D * 2);
    u16* ecth = (u16*)alloc((size_t)LABP * EXP2 * 2);
    size_t rem = ws_size - off;
    int splits = 16;
    size_t need16 = (size_t)16 * B_ROWS * LABP * 4 + (size_t)16 * 2 * B_ROWS * 4 + 1024;
    if (rem < need16) splits = 8;
    float* nump  = (float*)alloc((size_t)splits * B_ROWS * LABP * 4);
    float* denp2 = (float*)alloc((size_t)splits * 2 * B_ROWS * 4);

    proj_k<<<dim3(B_ROWS / 64, 8), 256, 0, stream>>>(features, g_weight, fnh, fnl, B_ROWS);
    proj_k<<<dim3(EXP2 / 64, 8), 256, 0, stream>>>(ex_features, g_weight, enh, enl, N_EX);
    l2norm_resplit_k<<<B_ROWS, 128, 0, stream>>>(fnh, fnl);
    l2norm_resplit_k<<<EXP2, 128, 0, stream>>>(enh, enl);
    ecrT_k<<<EXP2, 128, 0, stream>>>(ex_classes, class_reps, ecth);
    fused_k<<<dim3(B_ROWS / 128, splits), 256, 0, stream>>>(fnh, fnl, enh, enl, ecth, nump, denp2, splits);
    finalize_k<<<B_ROWS, 128, 0, stream>>>(nump, denp2, out, splits);
}

// Round 5
// 507.369 us; speedup vs baseline: 12.2321x; 1.0973x over previous
//
#include <hip/hip_runtime.h>

#define B_ROWS 4096
#define D      512
#define N_EX   20000
#define EXP2   20096     // N_EX padded to multiple of 128
#define N_LAB  100
#define LABP   112       // labels padded to 7x16
#define NT2    157       // EXP2 / 128

typedef __attribute__((ext_vector_type(8)))  short short8v;   // 8 bf16 (MFMA A/B frag)
typedef __attribute__((ext_vector_type(4)))  short short4v;
typedef __attribute__((ext_vector_type(4)))  float f32x4;
typedef __attribute__((ext_vector_type(16))) float f32x16;
typedef unsigned short u16;

__device__ __forceinline__ u16 f2bf(float x) {
    unsigned u = __builtin_bit_cast(unsigned, x);
    u = u + 0x7FFFu + ((u >> 16) & 1u);          // RNE
    return (u16)(u >> 16);
}
__device__ __forceinline__ float bf2f(u16 h) {
    unsigned u = ((unsigned)h) << 16;
    return __builtin_bit_cast(float, u);
}

__device__ __forceinline__ float wave_reduce_sum(float v) {
    #pragma unroll
    for (int off = 32; off > 0; off >>= 1) v += __shfl_down(v, off, 64);
    return v;
}

__device__ __forceinline__ void gload16(const void* g, void* l) {
    __builtin_amdgcn_global_load_lds((const __attribute__((address_space(1))) void*)g,
                                     (__attribute__((address_space(3))) void*)l, 16, 0, 0);
}

#define MFMA16(a, b, c) __builtin_amdgcn_mfma_f32_16x16x32_bf16((a), (b), (c), 0, 0, 0)
#define MFMA32(a, b, c) __builtin_amdgcn_mfma_f32_32x32x16_bf16((a), (b), (c), 0, 0, 0)

// ---------------- projection: C = X @ W^T (3-pass split-bf16), bf16 hi/lo out ----------------
__global__ __launch_bounds__(256, 2)
void proj_k(const float* __restrict__ X, const float* __restrict__ W,
            u16* __restrict__ Chi, u16* __restrict__ Clo, int M) {
    __shared__ u16 AH[64][72], AL[64][72], BH[64][72], BL[64][72];
    const int tid = threadIdx.x;
    const int lane = tid & 63, wave = tid >> 6;
    const int wm = wave >> 1, wn = wave & 1;
    const int l15 = lane & 15, l4 = lane >> 4;
    const int m0 = blockIdx.x * 64, n0 = blockIdx.y * 64;
    f32x4 acc[2][2] = {};
    for (int kc = 0; kc < 8; ++kc) {
        __syncthreads();
        #pragma unroll
        for (int s = 0; s < 2; ++s) {
            int ix = tid + s * 256;
            int r = ix >> 3, c = ix & 7;
            float va[8] = {0.f,0.f,0.f,0.f,0.f,0.f,0.f,0.f};
            if (m0 + r < M) {
                const float* p = &X[(size_t)(m0 + r) * D + kc * 64 + c * 8];
                float4 t0 = *(const float4*)p, t1 = *(const float4*)(p + 4);
                va[0]=t0.x; va[1]=t0.y; va[2]=t0.z; va[3]=t0.w;
                va[4]=t1.x; va[5]=t1.y; va[6]=t1.z; va[7]=t1.w;
            }
            short8v h, l;
            #pragma unroll
            for (int j = 0; j < 8; ++j) {
                u16 hh = f2bf(va[j]); h[j] = (short)hh; l[j] = (short)f2bf(va[j] - bf2f(hh));
            }
            *(short8v*)&AH[r][c*8] = h; *(short8v*)&AL[r][c*8] = l;
            const float* q = &W[(size_t)(n0 + r) * D + kc * 64 + c * 8];
            float4 s0 = *(const float4*)q, s1 = *(const float4*)(q + 4);
            float vb[8] = {s0.x,s0.y,s0.z,s0.w,s1.x,s1.y,s1.z,s1.w};
            #pragma unroll
            for (int j = 0; j < 8; ++j) {
                u16 hh = f2bf(vb[j]); h[j] = (short)hh; l[j] = (short)f2bf(vb[j] - bf2f(hh));
            }
            *(short8v*)&BH[r][c*8] = h; *(short8v*)&BL[r][c*8] = l;
        }
        __syncthreads();
        #pragma unroll
        for (int ks = 0; ks < 2; ++ks) {
            const int ko = ks * 32 + l4 * 8;
            short8v ah0 = *(const short8v*)&AH[wm*32      + l15][ko];
            short8v ah1 = *(const short8v*)&AH[wm*32 + 16 + l15][ko];
            short8v al0 = *(const short8v*)&AL[wm*32      + l15][ko];
            short8v al1 = *(const short8v*)&AL[wm*32 + 16 + l15][ko];
            short8v bh0 = *(const short8v*)&BH[wn*32      + l15][ko];
            short8v bh1 = *(const short8v*)&BH[wn*32 + 16 + l15][ko];
            short8v bl0 = *(const short8v*)&BL[wn*32      + l15][ko];
            short8v bl1 = *(const short8v*)&BL[wn*32 + 16 + l15][ko];
            acc[0][0] = MFMA16(ah0, bh0, acc[0][0]); acc[0][0] = MFMA16(ah0, bl0, acc[0][0]); acc[0][0] = MFMA16(al0, bh0, acc[0][0]);
            acc[0][1] = MFMA16(ah0, bh1, acc[0][1]); acc[0][1] = MFMA16(ah0, bl1, acc[0][1]); acc[0][1] = MFMA16(al0, bh1, acc[0][1]);
            acc[1][0] = MFMA16(ah1, bh0, acc[1][0]); acc[1][0] = MFMA16(ah1, bl0, acc[1][0]); acc[1][0] = MFMA16(al1, bh0, acc[1][0]);
            acc[1][1] = MFMA16(ah1, bh1, acc[1][1]); acc[1][1] = MFMA16(ah1, bl1, acc[1][1]); acc[1][1] = MFMA16(al1, bh1, acc[1][1]);
        }
    }
    #pragma unroll
    for (int mi = 0; mi < 2; ++mi)
      #pragma unroll
      for (int ni = 0; ni < 2; ++ni)
        #pragma unroll
        for (int r = 0; r < 4; ++r) {
            int row = m0 + wm*32 + mi*16 + l4*4 + r;
            int col = n0 + wn*32 + ni*16 + l15;
            float v = acc[mi][ni][r];
            u16 h = f2bf(v);
            Chi[(size_t)row * D + col] = h;
            Clo[(size_t)row * D + col] = f2bf(v - bf2f(h));
        }
}

// ---------------- in-place L2 row-normalize of bf16 hi/lo pair ----------------
__global__ __launch_bounds__(128)
void l2norm_resplit_k(u16* __restrict__ hi, u16* __restrict__ lo) {
    const int row = blockIdx.x, tid = threadIdx.x;
    const size_t base = (size_t)row * D + tid * 4;
    short4v hv = *(short4v*)&hi[base], lv = *(short4v*)&lo[base];
    float v[4]; float ss = 0.f;
    #pragma unroll
    for (int j = 0; j < 4; ++j) {
        v[j] = bf2f((u16)hv[j]) + bf2f((u16)lv[j]);
        ss += v[j] * v[j];
    }
    ss = wave_reduce_sum(ss);
    __shared__ float red[2];
    if ((tid & 63) == 0) red[tid >> 6] = ss;
    __syncthreads();
    float inv = 1.0f / fmaxf(sqrtf(red[0] + red[1]), 1e-12f);
    short4v ho, lo_;
    #pragma unroll
    for (int j = 0; j < 4; ++j) {
        float y = v[j] * inv;
        u16 h = f2bf(y); ho[j] = (short)h; lo_[j] = (short)f2bf(y - bf2f(h));
    }
    *(short4v*)&hi[base] = ho; *(short4v*)&lo[base] = lo_;
}

// ---------------- ecr^T: th[lab][e] = bf16 of (l1norm(exc[e]) @ creps)[lab] ----------------
__global__ __launch_bounds__(128)
void ecrT_k(const float* __restrict__ exc, const float* __restrict__ creps,
            u16* __restrict__ th) {
    const int e = blockIdx.x, tid = threadIdx.x;
    if (e >= N_EX) {
        if (tid < LABP) th[(size_t)tid * EXP2 + e] = 0;
        return;
    }
    __shared__ float aL[N_LAB];
    __shared__ float red[2];
    float v = 0.f;
    if (tid < N_LAB) { v = exc[(size_t)e * N_LAB + tid]; aL[tid] = v; }
    float s = wave_reduce_sum(fabsf(v));
    if ((tid & 63) == 0) red[tid >> 6] = s;
    __syncthreads();
    float inv = 1.0f / fmaxf(red[0] + red[1], 1e-12f);
    if (tid < LABP) {
        float acc = 0.f;
        if (tid < N_LAB) {
            for (int c = 0; c < N_LAB; ++c) acc += aL[c] * creps[c * N_LAB + tid];
            acc *= inv;
        }
        th[(size_t)tid * EXP2 + e] = f2bf(acc);
    }
}

// ---------------- fused main ----------------
// s = (fn_hi+fn_lo) @ en_hi^T  (32x32x16, 2-pass split-bf16), cube, den,
// num = a3 @ ecr (16x16x32, 1-pass). ecr^T tile has a persistent 28KB LDS home,
// DMA'd together with kc==7's staging so its latency drains under the same barrier.
__global__ __launch_bounds__(256, 2)
void fused_k(const u16* __restrict__ fnh, const u16* __restrict__ fnl,
             const u16* __restrict__ enh,
             const u16* __restrict__ ecth,
             float* __restrict__ nump, float* __restrict__ denp2, int splits) {
    // 48 KiB staging: SM[0]=A hi, SM[1]=A lo, SM[2]=B hi (linear rows, XOR-swizzled source).
    // Epilogue reuse: SM[0..1] -> a3 [128][128]. WT: persistent 28KB.
    __shared__ u16 SM[3][128][64];
    __shared__ u16 WT[LABP][128];
    u16* a3h = &SM[0][0][0];

    const int tid = threadIdx.x;
    const int l = tid & 63, w = tid >> 6;
    const int wm = w >> 1, wn = w & 1;
    const int l31 = l & 31, l5 = l >> 5;
    const int l15 = l & 15, l4 = l >> 4;
    const int m0 = blockIdx.x * 128;
    const int split = blockIdx.y;

    const int r_in = l >> 3;                   // staging: row within 8-row chunk
    const int c16s = (l & 7) ^ r_in;           // pre-swizzled source chunk

    f32x4 num_acc[2][7] = {};
    float den_acc[2][16] = {};

    for (int t = split; t < NT2; t += splits) {
        const int e0 = t * 128;
        f32x16 sacc[2][2] = {};
        for (int kc = 0; kc < 8; ++kc) {
            __syncthreads();                   // prior LDS reads done
            const int kofs = kc * 64;
            #pragma unroll
            for (int i = 0; i < 4; ++i) {
                const int q = w * 4 + i;       // 16 chunks of 8 rows
                const int row = q * 8 + r_in;
                const size_t fo = (size_t)(m0 + row) * D + kofs + c16s * 8;
                const size_t eo_ = (size_t)(e0 + row) * D + kofs + c16s * 8;
                gload16(&fnh[fo], (u16*)&SM[0][0][0] + q * 512);
                gload16(&fnl[fo], (u16*)&SM[1][0][0] + q * 512);
                gload16(&enh[eo_], (u16*)&SM[2][0][0] + q * 512);
            }
            if (kc == 7) {
                // DMA the ecr^T tile (112x128 bf16) into its persistent home; drains
                // with this kc's barrier, fully hidden under kc=7's MFMA phase.
                #pragma unroll
                for (int p = 0; p < 7; ++p) {
                    const int row = p * 16 + w * 4 + (l >> 4);
                    const int ch = l & 15;
                    gload16(&ecth[(size_t)row * EXP2 + e0 + ((ch ^ (row & 7)) * 8)],
                            &WT[0][0] + (p * 16 + w * 4) * 128);
                }
            }
            __syncthreads();                   // vmcnt(0)+lgkm drained
            #pragma unroll
            for (int ks = 0; ks < 4; ++ks) {
                short8v ah[2], al[2], bh[2];
                #pragma unroll
                for (int mi = 0; mi < 2; ++mi) {
                    int row = wm * 64 + mi * 32 + l31;
                    int cc = ((ks * 2 + l5) ^ (row & 7)) * 8;
                    ah[mi] = *(const short8v*)&SM[0][row][cc];
                    al[mi] = *(const short8v*)&SM[1][row][cc];
                }
                #pragma unroll
                for (int ni = 0; ni < 2; ++ni) {
                    int row = wn * 64 + ni * 32 + l31;
                    int cc = ((ks * 2 + l5) ^ (row & 7)) * 8;
                    bh[ni] = *(const short8v*)&SM[2][row][cc];
                }
                #pragma unroll
                for (int mi = 0; mi < 2; ++mi)
                    #pragma unroll
                    for (int ni = 0; ni < 2; ++ni) {
                        sacc[mi][ni] = MFMA32(ah[mi], bh[ni], sacc[mi][ni]);
                        sacc[mi][ni] = MFMA32(al[mi], bh[ni], sacc[mi][ni]);
                    }
            }
        }
        __syncthreads();                       // all waves done reading staged A/B; WT ready
        // cube + den + deposit a3 into swizzled [128][128] LDS (SM[0..1])
        #pragma unroll
        for (int mi = 0; mi < 2; ++mi)
          #pragma unroll
          for (int ni = 0; ni < 2; ++ni)
            #pragma unroll
            for (int r = 0; r < 16; ++r) {
                float sv = sacc[mi][ni][r];
                float a3 = sv * sv * sv;
                den_acc[mi][r] += fabsf(a3);
                int row = wm * 64 + mi * 32 + (r & 3) + 8 * (r >> 2) + 4 * l5;
                int col = wn * 64 + ni * 32 + l31;
                a3h[row * 128 + (((col >> 3) ^ (row & 7)) * 8) + (col & 7)] = f2bf(a3);
            }
        __syncthreads();                       // deposits visible
        // num += a3 @ ecr_tile (1-pass bf16, all operands from LDS)
        #pragma unroll
        for (int eo = 0; eo < 4; ++eo) {
            short8v ph[2];
            #pragma unroll
            for (int mi2 = 0; mi2 < 2; ++mi2) {
                int row = w * 32 + mi2 * 16 + l15;
                int cc = ((eo * 4 + l4) ^ (row & 7)) * 8;
                ph[mi2] = *(const short8v*)&a3h[row * 128 + cc];
            }
            #pragma unroll
            for (int ni = 0; ni < 7; ++ni) {
                int row = ni * 16 + l15;
                int cc = ((eo * 4 + l4) ^ (row & 7)) * 8;
                short8v whv = *(const short8v*)&WT[row][cc];
                #pragma unroll
                for (int mi2 = 0; mi2 < 2; ++mi2)
                    num_acc[mi2][ni] = MFMA16(ph[mi2], whv, num_acc[mi2][ni]);
            }
        }
    }
    // den: reduce across the 32 lanes of each half-wave, write per-(split, wn) partials
    #pragma unroll
    for (int mi = 0; mi < 2; ++mi)
      #pragma unroll
      for (int r = 0; r < 16; ++r) {
        float v = den_acc[mi][r];
        v += __shfl_xor(v, 1);  v += __shfl_xor(v, 2);  v += __shfl_xor(v, 4);
        v += __shfl_xor(v, 8);  v += __shfl_xor(v, 16);
        if (l31 == 0) {
            int row = wm * 64 + mi * 32 + (r & 3) + 8 * (r >> 2) + 4 * l5;
            denp2[((size_t)split * 2 + wn) * B_ROWS + m0 + row] = v;
        }
      }
    // num partials
    #pragma unroll
    for (int mi2 = 0; mi2 < 2; ++mi2)
      #pragma unroll
      for (int ni = 0; ni < 7; ++ni)
        #pragma unroll
        for (int r = 0; r < 4; ++r) {
            int grow = m0 + w * 32 + mi2 * 16 + l4 * 4 + r;
            nump[((size_t)split * B_ROWS + grow) * LABP + ni * 16 + l15] = num_acc[mi2][ni][r];
        }
}

// ---------------- finalize ----------------
__global__ __launch_bounds__(128)
void finalize_k(const float* __restrict__ nump, const float* __restrict__ denp2,
                float* __restrict__ out, int splits) {
    const int row = blockIdx.x, tid = threadIdx.x;
    float den = 0.f;
    for (int s = 0; s < splits; ++s)
        den += denp2[((size_t)s * 2 + 0) * B_ROWS + row] + denp2[((size_t)s * 2 + 1) * B_ROWS + row];
    if (tid < N_LAB) {
        float acc = 0.f;
        for (int s = 0; s < splits; ++s)
            acc += nump[((size_t)s * B_ROWS + row) * LABP + tid];
        out[(size_t)row * N_LAB + tid] = acc / fmaxf(den, 1e-12f);
    }
}

extern "C" void kernel_launch(void* const* d_in, const int* in_sizes, int n_in,
                              void* d_out, int out_size, void* d_ws, size_t ws_size,
                              hipStream_t stream) {
    (void)in_sizes; (void)n_in; (void)out_size;
    const float* features    = (const float*)d_in[0];
    const float* g_weight    = (const float*)d_in[1];
    const float* ex_features = (const float*)d_in[2];
    const float* ex_classes  = (const float*)d_in[3];
    const float* class_reps  = (const float*)d_in[4];
    float* out = (float*)d_out;

    size_t off = 0;
    auto alloc = [&](size_t bytes) {
        void* p = (char*)d_ws + off;
        off += (bytes + 255) & ~(size_t)255;
        return p;
    };
    u16* fnh = (u16*)alloc((size_t)B_ROWS * D * 2);
    u16* fnl = (u16*)alloc((size_t)B_ROWS * D * 2);
    u16* enh = (u16*)alloc((size_t)EXP2 * D * 2);
    u16* enl = (u16*)alloc((size_t)EXP2 * D * 2);   // used only for exact l2norm
    u16* ecth = (u16*)alloc((size_t)LABP * EXP2 * 2);
    size_t rem = ws_size - off;
    int splits = 16;
    size_t need16 = (size_t)16 * B_ROWS * LABP * 4 + (size_t)16 * 2 * B_ROWS * 4 + 1024;
    if (rem < need16) splits = 8;
    float* nump  = (float*)alloc((size_t)splits * B_ROWS * LABP * 4);
    float* denp2 = (float*)alloc((size_t)splits * 2 * B_ROWS * 4);

    proj_k<<<dim3(B_ROWS / 64, 8), 256, 0, stream>>>(features, g_weight, fnh, fnl, B_ROWS);
    proj_k<<<dim3(EXP2 / 64, 8), 256, 0, stream>>>(ex_features, g_weight, enh, enl, N_EX);
    l2norm_resplit_k<<<B_ROWS, 128, 0, stream>>>(fnh, fnl);
    l2norm_resplit_k<<<EXP2, 128, 0, stream>>>(enh, enl);
    ecrT_k<<<EXP2, 128, 0, stream>>>(ex_classes, class_reps, ecth);
    fused_k<<<dim3(B_ROWS / 128, splits), 256, 0, stream>>>(fnh, fnl, enh, ecth, nump, denp2, splits);
    finalize_k<<<B_ROWS, 128, 0, stream>>>(nump, denp2, out, splits);
}

// Round 6
// 507.000 us; speedup vs baseline: 12.2410x; 1.0007x over previous
//
#include <hip/hip_runtime.h>

#define B_ROWS 4096
#define D      512
#define N_EX   20000
#define EXP2   20096     // N_EX padded to multiple of 128
#define N_LAB  100
#define LABP2  128       // labels padded to 4x32 (rows 100..127 zero)
#define NT2    157       // EXP2 / 128
#define SPLITS 16

typedef __attribute__((ext_vector_type(8)))  short short8v;   // 8 bf16 (MFMA A/B frag)
typedef __attribute__((ext_vector_type(4)))  short short4v;
typedef __attribute__((ext_vector_type(4)))  float f32x4;
typedef __attribute__((ext_vector_type(16))) float f32x16;
typedef __attribute__((ext_vector_type(2)))  int   int2v;
typedef unsigned short u16;

__device__ __forceinline__ u16 f2bf(float x) {
    unsigned u = __builtin_bit_cast(unsigned, x);
    u = u + 0x7FFFu + ((u >> 16) & 1u);          // RNE
    return (u16)(u >> 16);
}
__device__ __forceinline__ float bf2f(u16 h) {
    unsigned u = ((unsigned)h) << 16;
    return __builtin_bit_cast(float, u);
}

__device__ __forceinline__ float wave_reduce_sum(float v) {
    #pragma unroll
    for (int off = 32; off > 0; off >>= 1) v += __shfl_down(v, off, 64);
    return v;
}

__device__ __forceinline__ void gload16(const void* g, void* l) {
    __builtin_amdgcn_global_load_lds((const __attribute__((address_space(1))) void*)g,
                                     (__attribute__((address_space(3))) void*)l, 16, 0, 0);
}

__device__ __forceinline__ unsigned pk_bf16(float a, float b) {
    unsigned r;
    asm("v_cvt_pk_bf16_f32 %0, %1, %2" : "=v"(r) : "v"(a), "v"(b));
    return r;
}

// (a', b') = ( (a.lo32, b.lo32), (a.hi32, b.hi32) )  -- lane-half exchange
__device__ __forceinline__ void swap_halves(unsigned &a, unsigned &b) {
#if __has_builtin(__builtin_amdgcn_permlane32_swap)
    int2v r = __builtin_amdgcn_permlane32_swap((int)a, (int)b, false, false);
    a = (unsigned)r[0]; b = (unsigned)r[1];
#else
    unsigned sa = (unsigned)__shfl_xor((int)a, 32, 64);
    unsigned sb = (unsigned)__shfl_xor((int)b, 32, 64);
    if (threadIdx.x & 32) a = sb; else b = sa;
#endif
}

#define MFMA16(a, b, c) __builtin_amdgcn_mfma_f32_16x16x32_bf16((a), (b), (c), 0, 0, 0)
#define MFMA32(a, b, c) __builtin_amdgcn_mfma_f32_32x32x16_bf16((a), (b), (c), 0, 0, 0)

// ---------------- projection: C = X @ W^T (3-pass split-bf16), bf16 hi(/lo) out ----------------
__global__ __launch_bounds__(256, 2)
void proj_k(const float* __restrict__ X, const float* __restrict__ W,
            u16* __restrict__ Chi, u16* __restrict__ Clo, int M) {
    __shared__ u16 AH[64][72], AL[64][72], BH[64][72], BL[64][72];
    const int tid = threadIdx.x;
    const int lane = tid & 63, wave = tid >> 6;
    const int wm = wave >> 1, wn = wave & 1;
    const int l15 = lane & 15, l4 = lane >> 4;
    const int m0 = blockIdx.x * 64, n0 = blockIdx.y * 64;
    f32x4 acc[2][2] = {};
    for (int kc = 0; kc < 8; ++kc) {
        __syncthreads();
        #pragma unroll
        for (int s = 0; s < 2; ++s) {
            int ix = tid + s * 256;
            int r = ix >> 3, c = ix & 7;
            float va[8] = {0.f,0.f,0.f,0.f,0.f,0.f,0.f,0.f};
            if (m0 + r < M) {
                const float* p = &X[(size_t)(m0 + r) * D + kc * 64 + c * 8];
                float4 t0 = *(const float4*)p, t1 = *(const float4*)(p + 4);
                va[0]=t0.x; va[1]=t0.y; va[2]=t0.z; va[3]=t0.w;
                va[4]=t1.x; va[5]=t1.y; va[6]=t1.z; va[7]=t1.w;
            }
            short8v h, l;
            #pragma unroll
            for (int j = 0; j < 8; ++j) {
                u16 hh = f2bf(va[j]); h[j] = (short)hh; l[j] = (short)f2bf(va[j] - bf2f(hh));
            }
            *(short8v*)&AH[r][c*8] = h; *(short8v*)&AL[r][c*8] = l;
            const float* q = &W[(size_t)(n0 + r) * D + kc * 64 + c * 8];
            float4 s0 = *(const float4*)q, s1 = *(const float4*)(q + 4);
            float vb[8] = {s0.x,s0.y,s0.z,s0.w,s1.x,s1.y,s1.z,s1.w};
            #pragma unroll
            for (int j = 0; j < 8; ++j) {
                u16 hh = f2bf(vb[j]); h[j] = (short)hh; l[j] = (short)f2bf(vb[j] - bf2f(hh));
            }
            *(short8v*)&BH[r][c*8] = h; *(short8v*)&BL[r][c*8] = l;
        }
        __syncthreads();
        #pragma unroll
        for (int ks = 0; ks < 2; ++ks) {
            const int ko = ks * 32 + l4 * 8;
            short8v ah0 = *(const short8v*)&AH[wm*32      + l15][ko];
            short8v ah1 = *(const short8v*)&AH[wm*32 + 16 + l15][ko];
            short8v al0 = *(const short8v*)&AL[wm*32      + l15][ko];
            short8v al1 = *(const short8v*)&AL[wm*32 + 16 + l15][ko];
            short8v bh0 = *(const short8v*)&BH[wn*32      + l15][ko];
            short8v bh1 = *(const short8v*)&BH[wn*32 + 16 + l15][ko];
            short8v bl0 = *(const short8v*)&BL[wn*32      + l15][ko];
            short8v bl1 = *(const short8v*)&BL[wn*32 + 16 + l15][ko];
            acc[0][0] = MFMA16(ah0, bh0, acc[0][0]); acc[0][0] = MFMA16(ah0, bl0, acc[0][0]); acc[0][0] = MFMA16(al0, bh0, acc[0][0]);
            acc[0][1] = MFMA16(ah0, bh1, acc[0][1]); acc[0][1] = MFMA16(ah0, bl1, acc[0][1]); acc[0][1] = MFMA16(al0, bh1, acc[0][1]);
            acc[1][0] = MFMA16(ah1, bh0, acc[1][0]); acc[1][0] = MFMA16(ah1, bl0, acc[1][0]); acc[1][0] = MFMA16(al1, bh0, acc[1][0]);
            acc[1][1] = MFMA16(ah1, bh1, acc[1][1]); acc[1][1] = MFMA16(ah1, bl1, acc[1][1]); acc[1][1] = MFMA16(al1, bh1, acc[1][1]);
        }
    }
    #pragma unroll
    for (int mi = 0; mi < 2; ++mi)
      #pragma unroll
      for (int ni = 0; ni < 2; ++ni)
        #pragma unroll
        for (int r = 0; r < 4; ++r) {
            int row = m0 + wm*32 + mi*16 + l4*4 + r;
            int col = n0 + wn*32 + ni*16 + l15;
            float v = acc[mi][ni][r];
            u16 h = f2bf(v);
            Chi[(size_t)row * D + col] = h;
            if (Clo) Clo[(size_t)row * D + col] = f2bf(v - bf2f(h));
        }
}

// ---------------- in-place L2 row-normalize of bf16 (hi or hi/lo pair) ----------------
__global__ __launch_bounds__(128)
void l2norm_resplit_k(u16* __restrict__ hi, u16* __restrict__ lo) {
    const int row = blockIdx.x, tid = threadIdx.x;
    const size_t base = (size_t)row * D + tid * 4;
    short4v hv = *(short4v*)&hi[base];
    float v[4]; float ss = 0.f;
    if (lo) {
        short4v lv = *(short4v*)&lo[base];
        #pragma unroll
        for (int j = 0; j < 4; ++j) v[j] = bf2f((u16)hv[j]) + bf2f((u16)lv[j]);
    } else {
        #pragma unroll
        for (int j = 0; j < 4; ++j) v[j] = bf2f((u16)hv[j]);
    }
    #pragma unroll
    for (int j = 0; j < 4; ++j) ss += v[j] * v[j];
    ss = wave_reduce_sum(ss);
    __shared__ float red[2];
    if ((tid & 63) == 0) red[tid >> 6] = ss;
    __syncthreads();
    float inv = 1.0f / fmaxf(sqrtf(red[0] + red[1]), 1e-12f);
    short4v ho, lo_;
    #pragma unroll
    for (int j = 0; j < 4; ++j) {
        float y = v[j] * inv;
        u16 h = f2bf(y); ho[j] = (short)h; lo_[j] = (short)f2bf(y - bf2f(h));
    }
    *(short4v*)&hi[base] = ho;
    if (lo) *(short4v*)&lo[base] = lo_;
}

// ---------------- ecr^T: th[lab][e] = bf16 of (l1norm(exc[e]) @ creps)[lab], 128 rows ----------------
__global__ __launch_bounds__(128)
void ecrT_k(const float* __restrict__ exc, const float* __restrict__ creps,
            u16* __restrict__ th) {
    const int e = blockIdx.x, tid = threadIdx.x;
    if (e >= N_EX) {
        th[(size_t)tid * EXP2 + e] = 0;
        return;
    }
    __shared__ float aL[N_LAB];
    __shared__ float red[2];
    float v = 0.f;
    if (tid < N_LAB) { v = exc[(size_t)e * N_LAB + tid]; aL[tid] = v; }
    float s = wave_reduce_sum(fabsf(v));
    if ((tid & 63) == 0) red[tid >> 6] = s;
    __syncthreads();
    float inv = 1.0f / fmaxf(red[0] + red[1], 1e-12f);
    float acc = 0.f;
    if (tid < N_LAB) {
        for (int c = 0; c < N_LAB; ++c) acc += aL[c] * creps[c * N_LAB + tid];
        acc *= inv;
    }
    th[(size_t)tid * EXP2 + e] = f2bf(acc);   // rows 100..127 get 0
}

// ---------------- fused main ----------------
// s^T = en_hi @ (fn_hi + fn_lo)^T  (32x32x16, 2-pass), cube in-register,
// num[m][lab] += a3 @ WT^T via in-register A-frags (cvt_pk + permlane32_swap),
// WT (ecr^T tile, 128x128 bf16, 32KB persistent LDS) DMA'd under kc==7's barrier.
__global__ __launch_bounds__(256, 2)
void fused_k(const u16* __restrict__ fnh, const u16* __restrict__ fnl,
             const u16* __restrict__ enh, const u16* __restrict__ ecth,
             float* __restrict__ nump, float* __restrict__ denp2) {
    __shared__ u16 SM[3][128][64];   // SM[0]=en hi (A), SM[1]=fn hi, SM[2]=fn lo (B); 48 KiB
    __shared__ u16 WT[LABP2][128];   // 32 KiB persistent

    const int tid = threadIdx.x;
    const int l = tid & 63, w = tid >> 6;
    const int we = w >> 1, wmcol = w & 1;   // wave owns e-half we*64, m-half wmcol*64
    const int l31 = l & 31, l5 = l >> 5;
    const int m0 = blockIdx.x * 128;
    const int split = blockIdx.y;

    const int r_in = l >> 3;                // staging: row within 8-row chunk
    const int c16s = (l & 7) ^ r_in;        // pre-swizzled source chunk

    union FragU { short8v s; unsigned u[4]; };

    f32x16 num_acc[2][4] = {};              // [mi][lab-tile] : D[m][lab] partial over wave's e
    float den_th[2] = {0.f, 0.f};

    for (int t = split; t < NT2; t += SPLITS) {
        const int e0 = t * 128;
        f32x16 sacc[2][2] = {};             // [ei][mi] : s^T frags, rows e, cols m
        for (int kc = 0; kc < 8; ++kc) {
            __syncthreads();                // prior LDS reads done
            const int kofs = kc * 64;
            #pragma unroll
            for (int i = 0; i < 4; ++i) {
                const int q = w * 4 + i;    // 16 chunks of 8 rows
                const int row = q * 8 + r_in;
                const size_t eo_ = (size_t)(e0 + row) * D + kofs + c16s * 8;
                const size_t fo  = (size_t)(m0 + row) * D + kofs + c16s * 8;
                gload16(&enh[eo_], (u16*)&SM[0][0][0] + q * 512);
                gload16(&fnh[fo],  (u16*)&SM[1][0][0] + q * 512);
                gload16(&fnl[fo],  (u16*)&SM[2][0][0] + q * 512);
            }
            if (kc == 7) {
                // DMA ecr^T tile (128x128 bf16) into persistent WT; drains at this
                // kc's second barrier, hidden under staging+MFMA.
                #pragma unroll
                for (int p = 0; p < 8; ++p) {
                    const int row = p * 16 + w * 4 + (l >> 4);
                    const int ch = l & 15;
                    gload16(&ecth[(size_t)row * EXP2 + e0 + ((ch ^ (row & 7)) * 8)],
                            &WT[0][0] + (p * 16 + w * 4) * 128);
                }
            }
            __syncthreads();                // vmcnt+lgkm drained
            #pragma unroll
            for (int ks = 0; ks < 4; ++ks) {
                short8v aE[2], bH[2], bL[2];
                #pragma unroll
                for (int ei = 0; ei < 2; ++ei) {
                    int row = we * 64 + ei * 32 + l31;
                    int cc = ((ks * 2 + l5) ^ (row & 7)) * 8;
                    aE[ei] = *(const short8v*)&SM[0][row][cc];
                }
                #pragma unroll
                for (int mi = 0; mi < 2; ++mi) {
                    int row = wmcol * 64 + mi * 32 + l31;
                    int cc = ((ks * 2 + l5) ^ (row & 7)) * 8;
                    bH[mi] = *(const short8v*)&SM[1][row][cc];
                    bL[mi] = *(const short8v*)&SM[2][row][cc];
                }
                #pragma unroll
                for (int ei = 0; ei < 2; ++ei)
                    #pragma unroll
                    for (int mi = 0; mi < 2; ++mi) {
                        sacc[ei][mi] = MFMA32(aE[ei], bH[mi], sacc[ei][mi]);
                        sacc[ei][mi] = MFMA32(aE[ei], bL[mi], sacc[ei][mi]);
                    }
            }
        }
        // cube + den + num, entirely register-local per wave (no barrier needed)
        #pragma unroll
        for (int ei = 0; ei < 2; ++ei) {
            FragU fr[2][2];                 // [mi][c] : a3 A-frags (rows m, k=e 16-chunk)
            #pragma unroll
            for (int mi = 0; mi < 2; ++mi) {
                float a3[16];
                #pragma unroll
                for (int r = 0; r < 16; ++r) {
                    float sv = sacc[ei][mi][r];
                    float c3 = sv * sv * sv;
                    a3[r] = c3;
                    den_th[mi] += fabsf(c3);
                }
                #pragma unroll
                for (int c = 0; c < 2; ++c) {
                    unsigned p01 = pk_bf16(a3[c*8+0], a3[c*8+1]);
                    unsigned p23 = pk_bf16(a3[c*8+2], a3[c*8+3]);
                    unsigned p45 = pk_bf16(a3[c*8+4], a3[c*8+5]);
                    unsigned p67 = pk_bf16(a3[c*8+6], a3[c*8+7]);
                    swap_halves(p01, p45);  // -> u[0], u[2]
                    swap_halves(p23, p67);  // -> u[1], u[3]
                    fr[mi][c].u[0] = p01; fr[mi][c].u[1] = p23;
                    fr[mi][c].u[2] = p45; fr[mi][c].u[3] = p67;
                }
            }
            #pragma unroll
            for (int c = 0; c < 2; ++c) {
                const int kch = we * 4 + ei * 2 + c;   // e-chunk16 within tile
                #pragma unroll
                for (int lt = 0; lt < 4; ++lt) {
                    int row = lt * 32 + l31;
                    int cc = ((kch * 2 + l5) ^ (row & 7)) * 8;
                    short8v wf = *(const short8v*)&WT[row][cc];  // B-frag: col=lab, k=e
                    num_acc[0][lt] = MFMA32(fr[0][c].s, wf, num_acc[0][lt]);
                    num_acc[1][lt] = MFMA32(fr[1][c].s, wf, num_acc[1][lt]);
                }
            }
        }
    }

    // den: lanes l and l+32 hold same m, disjoint e -> xor-32 reduce; per-(split,we) partial
    #pragma unroll
    for (int mi = 0; mi < 2; ++mi) {
        float v = den_th[mi];
        v += __shfl_xor(v, 32, 64);
        if (l5 == 0)
            denp2[((size_t)split * 2 + we) * B_ROWS + m0 + wmcol * 64 + mi * 32 + l31] = v;
    }

    // num: merge the two e-half partials (we=1 -> LDS -> we=0 adds) then coalesced store
    float* SMf = (float*)&SM[0][0][0];      // [64][133] f32 = 34 KB, within SM
    __syncthreads();                        // all staging/frag reads done before SM reuse
    #pragma unroll
    for (int mi = 0; mi < 2; ++mi) {
        if (we == 1) {
            #pragma unroll
            for (int lt = 0; lt < 4; ++lt)
                #pragma unroll
                for (int r = 0; r < 16; ++r) {
                    int rowf = (r & 3) + 8 * (r >> 2) + 4 * l5;
                    SMf[(wmcol * 32 + rowf) * 133 + lt * 32 + l31] = num_acc[mi][lt][r];
                }
        }
        __syncthreads();
        if (we == 0) {
            #pragma unroll
            for (int lt = 0; lt < 4; ++lt)
                #pragma unroll
                for (int r = 0; r < 16; ++r) {
                    int rowf = (r & 3) + 8 * (r >> 2) + 4 * l5;
                    float v = num_acc[mi][lt][r] + SMf[(wmcol * 32 + rowf) * 133 + lt * 32 + l31];
                    int m = m0 + wmcol * 64 + mi * 32 + rowf;
                    nump[((size_t)split * B_ROWS + m) * LABP2 + lt * 32 + l31] = v;
                }
        }
        __syncthreads();
    }
}

// ---------------- finalize ----------------
__global__ __launch_bounds__(128)
void finalize_k(const float* __restrict__ nump, const float* __restrict__ denp2,
                float* __restrict__ out) {
    const int row = blockIdx.x, tid = threadIdx.x;
    float den = 0.f;
    for (int s = 0; s < 2 * SPLITS; ++s)
        den += denp2[(size_t)s * B_ROWS + row];
    if (tid < N_LAB) {
        float acc = 0.f;
        for (int s = 0; s < SPLITS; ++s)
            acc += nump[((size_t)s * B_ROWS + row) * LABP2 + tid];
        out[(size_t)row * N_LAB + tid] = acc / fmaxf(den, 1e-12f);
    }
}

extern "C" void kernel_launch(void* const* d_in, const int* in_sizes, int n_in,
                              void* d_out, int out_size, void* d_ws, size_t ws_size,
                              hipStream_t stream) {
    (void)in_sizes; (void)n_in; (void)out_size; (void)ws_size;
    const float* features    = (const float*)d_in[0];
    const float* g_weight    = (const float*)d_in[1];
    const float* ex_features = (const float*)d_in[2];
    const float* ex_classes  = (const float*)d_in[3];
    const float* class_reps  = (const float*)d_in[4];
    float* out = (float*)d_out;

    size_t off = 0;
    auto alloc = [&](size_t bytes) {
        void* p = (char*)d_ws + off;
        off += (bytes + 255) & ~(size_t)255;
        return p;
    };
    u16* fnh = (u16*)alloc((size_t)B_ROWS * D * 2);        // 4.2 MB
    u16* fnl = (u16*)alloc((size_t)B_ROWS * D * 2);        // 4.2 MB
    u16* enh = (u16*)alloc((size_t)EXP2 * D * 2);          // 20.6 MB
    u16* ecth = (u16*)alloc((size_t)LABP2 * EXP2 * 2);     // 5.1 MB
    float* nump  = (float*)alloc((size_t)SPLITS * B_ROWS * LABP2 * 4);  // 33.6 MB
    float* denp2 = (float*)alloc((size_t)2 * SPLITS * B_ROWS * 4);      // 0.5 MB

    proj_k<<<dim3(B_ROWS / 64, 8), 256, 0, stream>>>(features, g_weight, fnh, fnl, B_ROWS);
    proj_k<<<dim3(EXP2 / 64, 8), 256, 0, stream>>>(ex_features, g_weight, enh, nullptr, N_EX);
    l2norm_resplit_k<<<B_ROWS, 128, 0, stream>>>(fnh, fnl);
    l2norm_resplit_k<<<EXP2, 128, 0, stream>>>(enh, nullptr);
    ecrT_k<<<EXP2, 128, 0, stream>>>(ex_classes, class_reps, ecth);
    fused_k<<<dim3(B_ROWS / 128, SPLITS), 256, 0, stream>>>(fnh, fnl, enh, ecth, nump, denp2);
    finalize_k<<<B_ROWS, 128, 0, stream>>>(nump, denp2, out);
}

// Round 7
// 420.244 us; speedup vs baseline: 14.7681x; 1.2064x over previous
//
#include <hip/hip_runtime.h>

#define B_ROWS 4096
#define D      512
#define N_EX   20000
#define EXP2   20096     // N_EX padded to multiple of 128
#define N_LAB  100
#define LABP2  128       // labels padded to 4x32 (rows 100..127 zero)
#define NT2    157       // EXP2 / 128
#define SPLITS 16

typedef __attribute__((ext_vector_type(8)))  short short8v;   // 8 bf16 (MFMA A/B frag)
typedef __attribute__((ext_vector_type(4)))  short short4v;
typedef __attribute__((ext_vector_type(4)))  float f32x4;
typedef __attribute__((ext_vector_type(16))) float f32x16;
typedef __attribute__((ext_vector_type(2)))  int   int2v;
typedef unsigned short u16;

__device__ __forceinline__ u16 f2bf(float x) {
    unsigned u = __builtin_bit_cast(unsigned, x);
    u = u + 0x7FFFu + ((u >> 16) & 1u);          // RNE
    return (u16)(u >> 16);
}
__device__ __forceinline__ float bf2f(u16 h) {
    unsigned u = ((unsigned)h) << 16;
    return __builtin_bit_cast(float, u);
}

__device__ __forceinline__ float wave_reduce_sum(float v) {
    #pragma unroll
    for (int off = 32; off > 0; off >>= 1) v += __shfl_down(v, off, 64);
    return v;
}

__device__ __forceinline__ void gload16(const void* g, void* l) {
    __builtin_amdgcn_global_load_lds((const __attribute__((address_space(1))) void*)g,
                                     (__attribute__((address_space(3))) void*)l, 16, 0, 0);
}

__device__ __forceinline__ unsigned pk_bf16(float a, float b) {
    unsigned r;
    asm("v_cvt_pk_bf16_f32 %0, %1, %2" : "=v"(r) : "v"(a), "v"(b));
    return r;
}

// (a', b') = ( (a.lo32, b.lo32), (a.hi32, b.hi32) )  -- lane-half exchange
__device__ __forceinline__ void swap_halves(unsigned &a, unsigned &b) {
#if __has_builtin(__builtin_amdgcn_permlane32_swap)
    int2v r = __builtin_amdgcn_permlane32_swap((int)a, (int)b, false, false);
    a = (unsigned)r[0]; b = (unsigned)r[1];
#else
    unsigned sa = (unsigned)__shfl_xor((int)a, 32, 64);
    unsigned sb = (unsigned)__shfl_xor((int)b, 32, 64);
    if (threadIdx.x & 32) a = sb; else b = sa;
#endif
}

#define MFMA16(a, b, c) __builtin_amdgcn_mfma_f32_16x16x32_bf16((a), (b), (c), 0, 0, 0)
#define MFMA32(a, b, c) __builtin_amdgcn_mfma_f32_32x32x16_bf16((a), (b), (c), 0, 0, 0)

// ---------------- projection: C = X @ W^T (2-pass: (Xhi+Xlo)*Whi), bf16 hi out ----------------
__global__ __launch_bounds__(256, 2)
void proj_k(const float* __restrict__ X, const float* __restrict__ W,
            u16* __restrict__ Chi, int M) {
    __shared__ u16 AH[64][72], AL[64][72], BH[64][72];
    const int tid = threadIdx.x;
    const int lane = tid & 63, wave = tid >> 6;
    const int wm = wave >> 1, wn = wave & 1;
    const int l15 = lane & 15, l4 = lane >> 4;
    const int m0 = blockIdx.x * 64, n0 = blockIdx.y * 64;
    f32x4 acc[2][2] = {};
    for (int kc = 0; kc < 8; ++kc) {
        __syncthreads();
        #pragma unroll
        for (int s = 0; s < 2; ++s) {
            int ix = tid + s * 256;
            int r = ix >> 3, c = ix & 7;
            float va[8] = {0.f,0.f,0.f,0.f,0.f,0.f,0.f,0.f};
            if (m0 + r < M) {
                const float* p = &X[(size_t)(m0 + r) * D + kc * 64 + c * 8];
                float4 t0 = *(const float4*)p, t1 = *(const float4*)(p + 4);
                va[0]=t0.x; va[1]=t0.y; va[2]=t0.z; va[3]=t0.w;
                va[4]=t1.x; va[5]=t1.y; va[6]=t1.z; va[7]=t1.w;
            }
            short8v h, l;
            #pragma unroll
            for (int j = 0; j < 8; ++j) {
                u16 hh = f2bf(va[j]); h[j] = (short)hh; l[j] = (short)f2bf(va[j] - bf2f(hh));
            }
            *(short8v*)&AH[r][c*8] = h; *(short8v*)&AL[r][c*8] = l;
            const float* q = &W[(size_t)(n0 + r) * D + kc * 64 + c * 8];
            float4 s0 = *(const float4*)q, s1 = *(const float4*)(q + 4);
            float vb[8] = {s0.x,s0.y,s0.z,s0.w,s1.x,s1.y,s1.z,s1.w};
            #pragma unroll
            for (int j = 0; j < 8; ++j) h[j] = (short)f2bf(vb[j]);
            *(short8v*)&BH[r][c*8] = h;
        }
        __syncthreads();
        #pragma unroll
        for (int ks = 0; ks < 2; ++ks) {
            const int ko = ks * 32 + l4 * 8;
            short8v ah0 = *(const short8v*)&AH[wm*32      + l15][ko];
            short8v ah1 = *(const short8v*)&AH[wm*32 + 16 + l15][ko];
            short8v al0 = *(const short8v*)&AL[wm*32      + l15][ko];
            short8v al1 = *(const short8v*)&AL[wm*32 + 16 + l15][ko];
            short8v bh0 = *(const short8v*)&BH[wn*32      + l15][ko];
            short8v bh1 = *(const short8v*)&BH[wn*32 + 16 + l15][ko];
            acc[0][0] = MFMA16(ah0, bh0, acc[0][0]); acc[0][0] = MFMA16(al0, bh0, acc[0][0]);
            acc[0][1] = MFMA16(ah0, bh1, acc[0][1]); acc[0][1] = MFMA16(al0, bh1, acc[0][1]);
            acc[1][0] = MFMA16(ah1, bh0, acc[1][0]); acc[1][0] = MFMA16(al1, bh0, acc[1][0]);
            acc[1][1] = MFMA16(ah1, bh1, acc[1][1]); acc[1][1] = MFMA16(al1, bh1, acc[1][1]);
        }
    }
    #pragma unroll
    for (int mi = 0; mi < 2; ++mi)
      #pragma unroll
      for (int ni = 0; ni < 2; ++ni)
        #pragma unroll
        for (int r = 0; r < 4; ++r) {
            int row = m0 + wm*32 + mi*16 + l4*4 + r;
            int col = n0 + wn*32 + ni*16 + l15;
            Chi[(size_t)row * D + col] = f2bf(acc[mi][ni][r]);
        }
}

// ---------------- in-place L2 row-normalize of bf16 ----------------
__global__ __launch_bounds__(128)
void l2norm_k(u16* __restrict__ hi) {
    const int row = blockIdx.x, tid = threadIdx.x;
    const size_t base = (size_t)row * D + tid * 4;
    short4v hv = *(short4v*)&hi[base];
    float v[4]; float ss = 0.f;
    #pragma unroll
    for (int j = 0; j < 4; ++j) { v[j] = bf2f((u16)hv[j]); ss += v[j] * v[j]; }
    ss = wave_reduce_sum(ss);
    __shared__ float red[2];
    if ((tid & 63) == 0) red[tid >> 6] = ss;
    __syncthreads();
    float inv = 1.0f / fmaxf(sqrtf(red[0] + red[1]), 1e-12f);
    short4v ho;
    #pragma unroll
    for (int j = 0; j < 4; ++j) ho[j] = (short)f2bf(v[j] * inv);
    *(short4v*)&hi[base] = ho;
}

// ---------------- ecr^T blocked: th[lab][e] = bf16((l1norm(exc[e]) @ creps)[lab]) ----------------
__global__ __launch_bounds__(256)
void ecrT_k(const float* __restrict__ exc, const float* __restrict__ creps,
            u16* __restrict__ th) {
    __shared__ float CRT[N_LAB][101];   // CRT[lab][c] = creps[c][lab]
    __shared__ float EX[128][N_LAB];
    __shared__ float INV[128];
    __shared__ u16 OUT[LABP2][128];
    const int tid = threadIdx.x;
    const int e0 = blockIdx.x * 128;
    for (int i = tid; i < N_LAB * N_LAB; i += 256) {
        int c = i / N_LAB, lab = i % N_LAB;
        CRT[lab][c] = creps[i];
    }
    for (int i = tid; i < 128 * N_LAB; i += 256) {
        int el = i / N_LAB, c = i % N_LAB;
        int e = e0 + el;
        EX[el][c] = (e < N_EX) ? exc[(size_t)e * N_LAB + c] : 0.f;
    }
    __syncthreads();
    if (tid < 128) {
        float s = 0.f;
        for (int c = 0; c < N_LAB; ++c) s += fabsf(EX[tid][c]);
        INV[tid] = 1.0f / fmaxf(s, 1e-12f);
    }
    __syncthreads();
    const int lab = tid & 127;
    for (int el = tid >> 7; el < 128; el += 2) {
        float acc = 0.f;
        if (lab < N_LAB) {
            #pragma unroll 4
            for (int c = 0; c < N_LAB; ++c) acc += EX[el][c] * CRT[lab][c];
            acc *= INV[el];
        }
        OUT[lab][el] = f2bf(acc);       // labs 100..127 -> 0
    }
    __syncthreads();
    for (int i = tid; i < LABP2 * 16; i += 256) {
        int lb = i >> 4, ch = i & 15;
        *(short8v*)&th[(size_t)lb * EXP2 + e0 + ch * 8] = *(const short8v*)&OUT[lb][ch * 8];
    }
}

// ---------------- fused main (512 threads, 8 waves) ----------------
// s^T = en_hi @ fn_hi^T  (32x32x16, 1-pass), cube in-register,
// num[m][lab] += a3 @ WT^T via in-register A-frags (cvt_pk + permlane32_swap).
// Wave w: e-half we = w>>2, m-quarter wq = w&3. 2 blocks/CU, 4 waves/SIMD.
__global__ __launch_bounds__(512, 4)
void fused_k(const u16* __restrict__ fnh, const u16* __restrict__ enh,
             const u16* __restrict__ ecth,
             float* __restrict__ nump, float* __restrict__ denp2) {
    __shared__ u16 SM[2][128][64];   // SM[0]=en (A), SM[1]=fn (B); 32 KiB
    __shared__ u16 WT[LABP2][128];   // 32 KiB persistent (ecr^T tile)

    const int tid = threadIdx.x;
    const int l = tid & 63, w = tid >> 6;
    const int we = w >> 2, wq = w & 3;
    const int l31 = l & 31, l5 = l >> 5;
    const int m0 = blockIdx.x * 128;
    const int split = blockIdx.y;
    const int r_in = l >> 3;
    const int c16s = (l & 7) ^ r_in;

    union FragU { short8v s; unsigned u[4]; };

    f32x16 num_acc[4] = {};          // [lab-tile]; D rows = m (wq's 32), cols = lab
    float den_th = 0.f;

    for (int t = split; t < NT2; t += SPLITS) {
        const int e0 = t * 128;
        f32x16 sacc[2] = {};         // [ei]: s^T frags, rows e, cols m
        for (int kc = 0; kc < 8; ++kc) {
            __syncthreads();
            const int kofs = kc * 64;
            #pragma unroll
            for (int i = 0; i < 2; ++i) {
                const int q = w * 2 + i;          // 16 chunk-groups of 8 rows
                const int row = q * 8 + r_in;
                gload16(&enh[(size_t)(e0 + row) * D + kofs + c16s * 8],
                        (u16*)&SM[0][0][0] + q * 512);
                gload16(&fnh[(size_t)(m0 + row) * D + kofs + c16s * 8],
                        (u16*)&SM[1][0][0] + q * 512);
            }
            if (kc == 7) {
                // DMA ecr^T tile (128x128 bf16) into WT; drains at this kc's barrier.
                #pragma unroll
                for (int p = 0; p < 4; ++p) {
                    const int row = p * 32 + w * 4 + (l >> 4);
                    const int ch = l & 15;
                    gload16(&ecth[(size_t)row * EXP2 + e0 + ((ch ^ (row & 7)) * 8)],
                            &WT[0][0] + (p * 32 + w * 4) * 128);
                }
            }
            __syncthreads();
            #pragma unroll
            for (int ks = 0; ks < 4; ++ks) {
                short8v aE[2], bF;
                #pragma unroll
                for (int ei = 0; ei < 2; ++ei) {
                    int row = we * 64 + ei * 32 + l31;
                    int cc = ((ks * 2 + l5) ^ (row & 7)) * 8;
                    aE[ei] = *(const short8v*)((const u16*)&SM[0][0][0] + row * 64 + cc);
                }
                {
                    int row = wq * 32 + l31;
                    int cc = ((ks * 2 + l5) ^ (row & 7)) * 8;
                    bF = *(const short8v*)((const u16*)&SM[1][0][0] + row * 64 + cc);
                }
                sacc[0] = MFMA32(aE[0], bF, sacc[0]);
                sacc[1] = MFMA32(aE[1], bF, sacc[1]);
            }
        }
        // cube + den + num, register-local (WT ready from kc==7 barrier)
        #pragma unroll
        for (int ei = 0; ei < 2; ++ei) {
            float a3[16];
            #pragma unroll
            for (int r = 0; r < 16; ++r) {
                float sv = sacc[ei][r];
                float c3 = sv * sv * sv;
                a3[r] = c3;
                den_th += fabsf(c3);
            }
            FragU fr[2];
            #pragma unroll
            for (int c = 0; c < 2; ++c) {
                unsigned p01 = pk_bf16(a3[c*8+0], a3[c*8+1]);
                unsigned p23 = pk_bf16(a3[c*8+2], a3[c*8+3]);
                unsigned p45 = pk_bf16(a3[c*8+4], a3[c*8+5]);
                unsigned p67 = pk_bf16(a3[c*8+6], a3[c*8+7]);
                swap_halves(p01, p45);
                swap_halves(p23, p67);
                fr[c].u[0] = p01; fr[c].u[1] = p23; fr[c].u[2] = p45; fr[c].u[3] = p67;
            }
            #pragma unroll
            for (int c = 0; c < 2; ++c) {
                const int kch = we * 4 + ei * 2 + c;       // e-chunk16 within tile
                #pragma unroll
                for (int lt = 0; lt < 4; ++lt) {
                    int row = lt * 32 + l31;
                    int cc = ((kch * 2 + l5) ^ (row & 7)) * 8;
                    short8v wf = *(const short8v*)(&WT[0][0] + row * 128 + cc);
                    num_acc[lt] = MFMA32(fr[c].s, wf, num_acc[lt]);
                }
            }
        }
    }

    // den: lanes l / l+32 hold same m, disjoint e
    {
        float v = den_th;
        v += __shfl_xor(v, 32, 64);
        if (l5 == 0)
            denp2[((size_t)split * 2 + we) * B_ROWS + m0 + wq * 32 + l31] = v;
    }

    // num: merge e-half partials through 32KB of SM (two wq-halves sequentially)
    float* SMf = (float*)&SM[0][0][0];   // 8192 f32
    __syncthreads();
    #pragma unroll
    for (int half = 0; half < 2; ++half) {
        if (we == 1 && (wq >> 1) == half) {
            #pragma unroll
            for (int lt = 0; lt < 4; ++lt)
                #pragma unroll
                for (int r = 0; r < 16; ++r) {
                    int rowf = (r & 3) + 8 * (r >> 2) + 4 * l5;
                    SMf[((wq & 1) * 32 + rowf) * 128 + lt * 32 + l31] = num_acc[lt][r];
                }
        }
        __syncthreads();
        if (we == 0 && (wq >> 1) == half) {
            #pragma unroll
            for (int lt = 0; lt < 4; ++lt)
                #pragma unroll
                for (int r = 0; r < 16; ++r) {
                    int rowf = (r & 3) + 8 * (r >> 2) + 4 * l5;
                    float v = num_acc[lt][r] + SMf[((wq & 1) * 32 + rowf) * 128 + lt * 32 + l31];
                    int m = m0 + wq * 32 + rowf;
                    nump[((size_t)split * B_ROWS + m) * LABP2 + lt * 32 + l31] = v;
                }
        }
        __syncthreads();
    }
}

// ---------------- finalize ----------------
__global__ __launch_bounds__(128)
void finalize_k(const float* __restrict__ nump, const float* __restrict__ denp2,
                float* __restrict__ out) {
    const int row = blockIdx.x, tid = threadIdx.x;
    float den = 0.f;
    for (int s = 0; s < 2 * SPLITS; ++s)
        den += denp2[(size_t)s * B_ROWS + row];
    if (tid < N_LAB) {
        float acc = 0.f;
        for (int s = 0; s < SPLITS; ++s)
            acc += nump[((size_t)s * B_ROWS + row) * LABP2 + tid];
        out[(size_t)row * N_LAB + tid] = acc / fmaxf(den, 1e-12f);
    }
}

extern "C" void kernel_launch(void* const* d_in, const int* in_sizes, int n_in,
                              void* d_out, int out_size, void* d_ws, size_t ws_size,
                              hipStream_t stream) {
    (void)in_sizes; (void)n_in; (void)out_size; (void)ws_size;
    const float* features    = (const float*)d_in[0];
    const float* g_weight    = (const float*)d_in[1];
    const float* ex_features = (const float*)d_in[2];
    const float* ex_classes  = (const float*)d_in[3];
    const float* class_reps  = (const float*)d_in[4];
    float* out = (float*)d_out;

    size_t off = 0;
    auto alloc = [&](size_t bytes) {
        void* p = (char*)d_ws + off;
        off += (bytes + 255) & ~(size_t)255;
        return p;
    };
    u16* fnh = (u16*)alloc((size_t)B_ROWS * D * 2);                     // 4.2 MB
    u16* enh = (u16*)alloc((size_t)EXP2 * D * 2);                       // 20.6 MB
    u16* ecth = (u16*)alloc((size_t)LABP2 * EXP2 * 2);                  // 5.1 MB
    float* nump  = (float*)alloc((size_t)SPLITS * B_ROWS * LABP2 * 4);  // 33.6 MB
    float* denp2 = (float*)alloc((size_t)2 * SPLITS * B_ROWS * 4);      // 0.5 MB

    proj_k<<<dim3(B_ROWS / 64, 8), 256, 0, stream>>>(features, g_weight, fnh, B_ROWS);
    proj_k<<<dim3(EXP2 / 64, 8), 256, 0, stream>>>(ex_features, g_weight, enh, N_EX);
    l2norm_k<<<B_ROWS, 128, 0, stream>>>(fnh);
    l2norm_k<<<EXP2, 128, 0, stream>>>(enh);
    ecrT_k<<<NT2, 256, 0, stream>>>(ex_classes, class_reps, ecth);
    fused_k<<<dim3(B_ROWS / 128, SPLITS), 512, 0, stream>>>(fnh, enh, ecth, nump, denp2);
    finalize_k<<<B_ROWS, 128, 0, stream>>>(nump, denp2, out);
}